// Round 23
// baseline (139.680 us; speedup 1.0000x reference)
//
#include <hip/hip_runtime.h>
#include <hip/hip_bf16.h>

// SelfAttention fused pipeline, bf16 MFMA path, K-split flash attention.
// x[4,512,48,48] -> GN(32) -> qkv 1x1 conv -> 8-head attn (N=2304,D=64) -> out proj.
// GN folded as per-channel affine into gemm_qkv's B staging (single x pass);
// final-norm (sum po)/l fused into the out-proj GEMM's B staging; l computed
// via ones-MFMA (no VALU reduction). SPLIT=4 -> grid 2304 = 9 blocks/CU even.
//
// ws layout (67.81 MB < 68.16 MB proven safe):
//   po0..3 [4][2304][512] bf16 @ 0, 9437184, 18874368, 28311552 (during/after attn)
//   xT     [4][2304][512] bf16 @ 0          (aliases po0; dead after gemm_qkv)
//   wq_bf  [1536][512] bf16    @ 9437184    (aliases po1; dead after gemm_qkv)
//   vsec   [4][512][2304] bf16 @ 37748736   (d-major, n-PERMUTED per 64-group)
//   qT     [4][8][2304][64] bf16 @ 47185920 (QSCALE folded at cast)
//   kT     [4][8][2304][64] bf16 @ 56623104
//   pl     [4][4][8][2304] f32  @ 66060288
//   part   [4][32][36] float2   @ 67239936  (GN partial sums per n-tile)
//   wo_bf  [512][512] bf16      @ 67276800
//   scsh   [4][512] float2      @ 67801088  (GN affine: xn = x*sc + sh)

typedef unsigned short u16;
typedef unsigned int u32;
typedef __attribute__((ext_vector_type(8))) short bf16x8;
typedef __attribute__((ext_vector_type(4))) float f32x4;
typedef __attribute__((ext_vector_type(8))) unsigned short us8;
typedef __attribute__((ext_vector_type(4))) unsigned short us4;

#define B_ 4
#define C_ 512
#define N_ 2304
#define H_ 8
#define D_ 64
#define G_ 32
#define SPLIT 4
#define NT (N_ / 64 / SPLIT)   // 9 k-tiles per split block

// log2(e)/8: folded into W_q at cast so QK^T lands in exp2 domain.
#define QSCALE 0.1803368801111204f
// No max subtraction: exp2-domain scores |s| <~ 12, exp2(s) <= ~4096 fits f32/bf16;
// softmax is shift-invariant.

__device__ __forceinline__ u16 f2bf(float f) {
  unsigned u = __float_as_uint(f);
  u += 0x7FFFu + ((u >> 16) & 1u);   // RNE
  return (u16)(u >> 16);
}
__device__ __forceinline__ float bf2f(u16 h) {
  return __uint_as_float(((unsigned)h) << 16);
}
__device__ __forceinline__ u32 pack2bf(float lo, float hi) {
  __hip_bfloat162 t = __float22bfloat162_rn(float2{lo, hi});
  u32 r;
  __builtin_memcpy(&r, &t, 4);
  return r;
}

// async global->LDS, 16B per lane. LDS dest = wave-uniform base + lane*16.
__device__ __forceinline__ void gload16(const void* g, void* l) {
  __builtin_amdgcn_global_load_lds(
      reinterpret_cast<const __attribute__((address_space(1))) unsigned int*>(
          reinterpret_cast<unsigned long long>(g)),
      reinterpret_cast<__attribute__((address_space(3))) unsigned int*>(
          static_cast<unsigned int>(reinterpret_cast<unsigned long long>(l))),
      16, 0, 0);
}

// ---------------- prep: weight cast (blocks 0-255) + x cast/transpose + GN partials ----------------
__global__ __launch_bounds__(256) void prep_all(
    const float* __restrict__ wq, const float* __restrict__ wo,
    u16* __restrict__ wq_bf, u16* __restrict__ wo_bf,
    const float* __restrict__ x, u16* __restrict__ xT, float2* __restrict__ part) {
  if (blockIdx.x < 256) {
    const int n1 = 1536 * 512 / 4, n2 = 512 * 512 / 4;
    const int nq = 512 * 512 / 4;   // q section in float4 units
    for (int i = blockIdx.x * 256 + threadIdx.x; i < n1 + n2; i += 256 * 256) {
      const float4 v = (i < n1) ? ((const float4*)wq)[i] : ((const float4*)wo)[i - n1];
      const float sc = (i < nq) ? QSCALE : 1.0f;
      us4 o; o[0] = f2bf(v.x * sc); o[1] = f2bf(v.y * sc); o[2] = f2bf(v.z * sc); o[3] = f2bf(v.w * sc);
      if (i < n1) ((us4*)wq_bf)[i] = o; else ((us4*)wo_bf)[i - n1] = o;
    }
    return;
  }
  __shared__ u16 T[64][72];
  const int bid = blockIdx.x - 256;            // 0..1151
  const int b = bid / 288, rem = bid % 288;
  const int c0 = (rem & 7) * 64, ni = rem >> 3;   // ni = n-tile 0..35
  const int n0 = ni * 64;
  const int tid = threadIdx.x;
  const int r = tid >> 2, ch = (tid & 3) * 16;
  const float* src = x + (size_t)(b * C_ + c0 + r) * N_ + n0 + ch;
  float s = 0.f, s2 = 0.f;
  #pragma unroll
  for (int j = 0; j < 16; j += 4) {
    const float4 v = *(const float4*)(src + j);
    s  += v.x + v.y + v.z + v.w;
    s2 += v.x * v.x + v.y * v.y + v.z * v.z + v.w * v.w;
    us4 o; o[0] = f2bf(v.x); o[1] = f2bf(v.y); o[2] = f2bf(v.z); o[3] = f2bf(v.w);
    *(us4*)&T[r][ch + j] = o;
  }
  // wave w = c-rows 16w..16w+15 = one group quarter; reduce across 64 lanes
  #pragma unroll
  for (int off = 32; off; off >>= 1) { s += __shfl_xor(s, off); s2 += __shfl_xor(s2, off); }
  if ((tid & 63) == 0) {
    const int g = (c0 >> 4) + (tid >> 6);
    part[((size_t)(b * G_) + g) * 36 + ni] = make_float2(s, s2);
  }
  __syncthreads();
  us8 o1, o2;
  #pragma unroll
  for (int j = 0; j < 8; j++) { o1[j] = T[ch + j][r]; o2[j] = T[ch + 8 + j][r]; }
  u16* dst = xT + (size_t)(b * N_ + n0 + r) * C_ + c0 + ch;
  *(us8*)dst = o1;
  *(us8*)(dst + 8) = o2;
}

// ---------------- finalize GN stats -> scsh[b][c] = (sc, sh) ----------------
__global__ __launch_bounds__(512) void make_scsh(
    const float2* __restrict__ part, const float* __restrict__ gamma,
    const float* __restrict__ beta, float2* __restrict__ scsh) {
  const int b = blockIdx.x, c = threadIdx.x;
  const float2* pp = part + (size_t)(b * G_ + (c >> 4)) * 36;
  float S = 0.f, S2 = 0.f;
  #pragma unroll 4
  for (int i = 0; i < 36; i++) { S += pp[i].x; S2 += pp[i].y; }
  const float inv = 1.f / (16.f * N_);
  const float mean = S * inv;
  const float rstd = rsqrtf(S2 * inv - mean * mean + 1e-5f);
  const float sc = rstd * gamma[c];
  scsh[b * C_ + c] = make_float2(sc, beta[c] - mean * sc);
}

// ---------------- QKV GEMM: 256x128 tile, BK=64, GN affine fused in B staging ----------------
__global__ __launch_bounds__(512) void gemm_qkv(
    const u16* __restrict__ A, const u16* __restrict__ xT,
    const float2* __restrict__ scsh,
    u16* __restrict__ qT, u16* __restrict__ kT, u16* __restrict__ vout) {
  __shared__ u16 As[256][64];
  __shared__ u16 Bs[128][64];
  const int tid = threadIdx.x;
  const int wave = tid >> 6, lane = tid & 63;
  const int l16 = lane & 15, lq = lane >> 4;

  // XCD-chunked bijective block swizzle over grid (6,18,4) = 432 (432%8==0).
  const int lin = blockIdx.x + 6 * (blockIdx.y + 18 * blockIdx.z);
  const int per = 432 >> 3;
  const int eff = (lin & 7) * per + (lin >> 3);
  const int m0 = (eff % 6) * 256;
  const int n0 = ((eff / 6) % 18) * 128;
  const int bz = eff / 108;

  const int wm = (wave >> 1) * 64, wn = (wave & 1) * 64;
  const u16* Bb = xT + (size_t)bz * N_ * C_;
  const float2* sb = scsh + bz * C_;

  f32x4 acc[4][4];
  #pragma unroll
  for (int mi = 0; mi < 4; mi++)
    #pragma unroll
    for (int ni = 0; ni < 4; ni++) {
      acc[mi][ni][0] = 0.f; acc[mi][ni][1] = 0.f; acc[mi][ni][2] = 0.f; acc[mi][ni][3] = 0.f;
    }

  const int h3r = lane >> 3;                 // row-within-8 this lane covers
  const int scg = ((lane & 7) ^ h3r) * 8;    // pre-swizzled global chunk (A)
  const int rdx = l16 & 7;                   // read-side XOR key
  for (int kt = 0; kt < C_; kt += 64) {
    __syncthreads();
    #pragma unroll
    for (int j = 0; j < 4; j++) {
      const int row = wave * 8 + j * 64 + h3r;   // (row & 7) == h3r
      gload16(&A[(size_t)(m0 + row) * C_ + kt + scg], &As[wave * 8 + j * 64][0]);
    }
    // B staging: raw xT us8 (linear chunk) -> GN affine -> swizzled ds_write
    {
      const int cbase = kt + (lane & 7) * 8;
      float2 sv[8];
      #pragma unroll
      for (int e = 0; e < 8; e++) sv[e] = sb[cbase + e];
      #pragma unroll
      for (int j = 0; j < 2; j++) {
        const int row = wave * 8 + j * 64 + h3r;
        const us8 xr = *(const us8*)&Bb[(size_t)(n0 + row) * C_ + cbase];
        us8 o;
        #pragma unroll
        for (int e = 0; e < 8; e++) o[e] = f2bf(bf2f(xr[e]) * sv[e].x + sv[e].y);
        *(us8*)&Bs[row][((lane & 7) ^ h3r) * 8] = o;
      }
    }
    __syncthreads();
    #pragma unroll
    for (int kk = 0; kk < 2; kk++) {
      bf16x8 af[4], bfr[4];
      #pragma unroll
      for (int mi = 0; mi < 4; mi++)
        af[mi] = *(const bf16x8*)&As[wm + mi * 16 + l16][(((kk << 2) | lq) ^ rdx) * 8];
      #pragma unroll
      for (int ni = 0; ni < 4; ni++)
        bfr[ni] = *(const bf16x8*)&Bs[wn + ni * 16 + l16][(((kk << 2) | lq) ^ rdx) * 8];
      #pragma unroll
      for (int mi = 0; mi < 4; mi++)
        #pragma unroll
        for (int ni = 0; ni < 4; ni++)
          acc[mi][ni] = __builtin_amdgcn_mfma_f32_16x16x32_bf16(af[mi], bfr[ni], acc[mi][ni], 0, 0, 0);
    }
  }
  #pragma unroll
  for (int mi = 0; mi < 4; mi++) {
    const int row0 = m0 + wm + mi * 16 + lq * 4;
    #pragma unroll
    for (int ni = 0; ni < 4; ni++) {
      const int col = n0 + wn + ni * 16 + l16;
      const int which = row0 >> 9;           // 0=q, 1=k, 2=v
      if (which < 2) {
        const int h = (row0 >> 6) & 7, d0 = row0 & 63;
        u16* dst = which ? kT : qT;
        us4 o;
        #pragma unroll
        for (int j = 0; j < 4; j++) o[j] = f2bf(acc[mi][ni][j]);
        *(us4*)&dst[((size_t)((bz * H_ + h) * N_) + col) * D_ + d0] = o;
      } else {
        // n-permute within 64-group: n = g32 + hi*16 + lq2*4 + j -> g32 + lq2*8 + hi*4 + j
        const int cp = (col & ~63) | (col & 32) | (((col >> 2) & 3) << 3) |
                       (((col >> 4) & 1) << 2) | (col & 3);
        #pragma unroll
        for (int j = 0; j < 4; j++)
          vout[((size_t)(bz * 512) + (row0 & 511) + j) * N_ + cp] = f2bf(acc[mi][ni][j]);
      }
    }
  }
}

// ---------------- out-proj GEMM with fused 4-way combine ----------------
// out[bz][m][n] = wo_bf[m][k] * (sum_sp po_sp / sum_sp l_sp) + bias; f32 output.
__global__ __launch_bounds__(256) void gemm_out_fused(
    const u16* __restrict__ po0, const u16* __restrict__ A,
    const float* __restrict__ pl, float* __restrict__ C, const float* __restrict__ bias) {
  __shared__ u16 As[128][64];
  __shared__ u16 Bs[128][64];
  const int tid = threadIdx.x;
  const int wave = tid >> 6, lane = tid & 63;
  const int l16 = lane & 15, lq = lane >> 4;

  // XCD-chunked bijective swizzle over grid (4,18,4) = 288 (288%8==0).
  const int lin = blockIdx.x + 4 * (blockIdx.y + 18 * blockIdx.z);
  const int per = 288 >> 3;
  const int eff = (lin & 7) * per + (lin >> 3);
  const int m0 = (eff % 4) * 128;
  const int n0 = ((eff / 4) % 18) * 128;
  const int bz = eff / 72;

  const int wm = (wave >> 1) * 64, wn = (wave & 1) * 64;

  f32x4 acc[4][4];
  #pragma unroll
  for (int mi = 0; mi < 4; mi++)
    #pragma unroll
    for (int ni = 0; ni < 4; ni++) {
      acc[mi][ni][0] = 0.f; acc[mi][ni][1] = 0.f; acc[mi][ni][2] = 0.f; acc[mi][ni][3] = 0.f;
    }

  const int h3r = lane >> 3;
  const int scg = ((lane & 7) ^ h3r) * 8;
  const int rdx = l16 & 7;
  const size_t lstr = (size_t)B_ * H_ * N_;
  const size_t pstr = (size_t)B_ * N_ * 512;
  for (int kt = 0; kt < C_; kt += 64) {
    __syncthreads();
    #pragma unroll
    for (int j = 0; j < 4; j++) {
      const int row = wave * 8 + j * 32 + h3r;
      gload16(&A[(size_t)(m0 + row) * C_ + kt + scg], &As[wave * 8 + j * 32][0]);
    }
    #pragma unroll
    for (int j = 0; j < 4; j++) {
      const int row = wave * 8 + j * 32 + h3r;
      const size_t pbase = ((size_t)(bz * N_) + n0 + row) * 512 + kt + (lane & 7) * 8;
      const us8 a0 = *(const us8*)&po0[pbase];
      const us8 a1 = *(const us8*)&po0[pbase + pstr];
      const us8 a2 = *(const us8*)&po0[pbase + 2 * pstr];
      const us8 a3 = *(const us8*)&po0[pbase + 3 * pstr];
      const size_t lidx = ((size_t)(bz * H_) + (kt >> 6)) * N_ + n0 + row;
      const float rl = 1.0f / (pl[lidx] + pl[lidx + lstr] + pl[lidx + 2 * lstr] + pl[lidx + 3 * lstr]);
      us8 o;
      #pragma unroll
      for (int e = 0; e < 8; e++)
        o[e] = f2bf(((bf2f(a0[e]) + bf2f(a1[e])) + (bf2f(a2[e]) + bf2f(a3[e]))) * rl);
      *(us8*)&Bs[row][((lane & 7) ^ h3r) * 8] = o;
    }
    __syncthreads();
    #pragma unroll
    for (int kk = 0; kk < 2; kk++) {
      bf16x8 af[4], bfr[4];
      #pragma unroll
      for (int mi = 0; mi < 4; mi++)
        af[mi] = *(const bf16x8*)&As[wm + mi * 16 + l16][(((kk << 2) | lq) ^ rdx) * 8];
      #pragma unroll
      for (int ni = 0; ni < 4; ni++)
        bfr[ni] = *(const bf16x8*)&Bs[wn + ni * 16 + l16][(((kk << 2) | lq) ^ rdx) * 8];
      #pragma unroll
      for (int mi = 0; mi < 4; mi++)
        #pragma unroll
        for (int ni = 0; ni < 4; ni++)
          acc[mi][ni] = __builtin_amdgcn_mfma_f32_16x16x32_bf16(af[mi], bfr[ni], acc[mi][ni], 0, 0, 0);
    }
  }
  #pragma unroll
  for (int mi = 0; mi < 4; mi++) {
    const int row0 = m0 + wm + mi * 16 + lq * 4;
    #pragma unroll
    for (int ni = 0; ni < 4; ni++) {
      const int col = n0 + wn + ni * 16 + l16;
      #pragma unroll
      for (int j = 0; j < 4; j++) {
        const size_t idx = ((size_t)bz * C_ + row0 + j) * N_ + col;
        C[idx] = acc[mi][ni][j] + bias[row0 + j];
      }
    }
  }
}

// ---------------- flash attention v23: SPLIT=4 (even grid) + l via ones-MFMA ----------------
// block = (h, q-tile of 128, b*SPLIT+sp), 8 waves x 16 q-rows, 9 k-tiles.
// Grid (8,18,16)=2304 = 9 blocks/CU exactly. l computed by an extra MFMA per
// kh with an all-ones B-operand (sums p over all 32 k-slots incl. cross-lane),
// deleting the per-tile VALU reduction and the epilogue shuffles.
__global__ __launch_bounds__(512) void attn_kernel23(
    const u16* __restrict__ qT, const u16* __restrict__ kT,
    const u16* __restrict__ vp, u16* __restrict__ po0,
    float* __restrict__ pl) {
  __shared__ u16 Ks[2][64][64];
  __shared__ u16 Vs[2][64][64];

  const int h = blockIdx.x;
  const int b = blockIdx.z >> 2, sp = blockIdx.z & 3;
  const int q0 = blockIdx.y * 128;
  const int tid = threadIdx.x;
  const int wave = tid >> 6, lane = tid & 63;
  const int l16 = lane & 15, lq = lane >> 4;
  const int h3 = l16 & 7;                  // read-side XOR key
  const int kt0 = sp * NT;

  bf16x8 qf[2];
  {
    const u16* qb = qT + ((size_t)((b * H_ + h) * N_ + q0 + wave * 16 + l16)) * D_;
    qf[0] = *(const bf16x8*)(qb + lq * 8);
    qf[1] = *(const bf16x8*)(qb + 32 + lq * 8);
  }

  f32x4 acc[4], lacc;
  #pragma unroll
  for (int di = 0; di < 4; di++) {
    acc[di][0] = 0.f; acc[di][1] = 0.f; acc[di][2] = 0.f; acc[di][3] = 0.f;
  }
  lacc[0] = 0.f; lacc[1] = 0.f; lacc[2] = 0.f; lacc[3] = 0.f;
  const f32x4 z4 = {0.f, 0.f, 0.f, 0.f};
  union { u32 w[4]; bf16x8 v; } ones;
  ones.w[0] = 0x3F803F80u; ones.w[1] = 0x3F803F80u;
  ones.w[2] = 0x3F803F80u; ones.w[3] = 0x3F803F80u;

  const u16* kbase = kT + (size_t)(b * H_ + h) * N_ * D_;
  const u16* vbase = vp + ((size_t)(b * 512) + h * D_) * N_;
  const int srow = wave * 8 + (lane >> 3);
  const int scg  = (((lane & 7) ^ (srow & 7))) * 8;

  gload16(&kbase[(size_t)(kt0 * 64 + srow) * D_ + scg], &Ks[0][wave * 8][0]);
  gload16(&vbase[(size_t)srow * N_ + kt0 * 64 + scg],   &Vs[0][wave * 8][0]);

  int cur = 0;
  for (int t = 0; t < NT; t++) {
    const int kt = kt0 + t;
    __syncthreads();

    if (t + 1 < NT) {
      gload16(&kbase[(size_t)((kt + 1) * 64 + srow) * D_ + scg], &Ks[cur ^ 1][wave * 8][0]);
      gload16(&vbase[(size_t)srow * N_ + (kt + 1) * 64 + scg],   &Vs[cur ^ 1][wave * 8][0]);
    }

    // ---- S^T = K Q^T ----
    f32x4 s[4];
    __builtin_amdgcn_s_setprio(1);
    #pragma unroll
    for (int ni = 0; ni < 4; ni++) {
      const bf16x8 k0 = *(const bf16x8*)&Ks[cur][ni * 16 + l16][(lq ^ h3) * 8];
      const bf16x8 k1 = *(const bf16x8*)&Ks[cur][ni * 16 + l16][((4 | lq) ^ h3) * 8];
      s[ni] = __builtin_amdgcn_mfma_f32_16x16x32_bf16(k0, qf[0], z4, 0, 0, 0);
      s[ni] = __builtin_amdgcn_mfma_f32_16x16x32_bf16(k1, qf[1], s[ni], 0, 0, 0);
    }
    __builtin_amdgcn_s_setprio(0);

    // ---- p = exp2(s); pack directly into PV a-frag words (no VALU l-sum) ----
    union { u32 w[4]; bf16x8 v; } af[2];
    #pragma unroll
    for (int ni = 0; ni < 4; ni++) {
      const float p0 = __builtin_amdgcn_exp2f(s[ni][0]);
      const float p1 = __builtin_amdgcn_exp2f(s[ni][1]);
      const float p2 = __builtin_amdgcn_exp2f(s[ni][2]);
      const float p3 = __builtin_amdgcn_exp2f(s[ni][3]);
      af[ni >> 1].w[(ni & 1) * 2]     = pack2bf(p0, p1);
      af[ni >> 1].w[(ni & 1) * 2 + 1] = pack2bf(p2, p3);
    }

    // ---- PV + l (ones-MFMA sums p over all k-slots incl. cross-lane) ----
    __builtin_amdgcn_s_setprio(1);
    #pragma unroll
    for (int kh = 0; kh < 2; kh++) {
      lacc = __builtin_amdgcn_mfma_f32_16x16x32_bf16(af[kh].v, ones.v, lacc, 0, 0, 0);
      #pragma unroll
      for (int di = 0; di < 4; di++) {
        const bf16x8 vf = *(const bf16x8*)&Vs[cur][di * 16 + l16][(((kh << 2) | lq) ^ h3) * 8];
        acc[di] = __builtin_amdgcn_mfma_f32_16x16x32_bf16(af[kh].v, vf, acc[di], 0, 0, 0);
      }
    }
    __builtin_amdgcn_s_setprio(0);

    cur ^= 1;
  }

  // ---- epilogue: write unnormalized partial O (bf16) + partial l ----
  u16* po = po0 + (size_t)sp * ((size_t)B_ * N_ * 512);
  if (l16 == 0) {
    #pragma unroll
    for (int j = 0; j < 4; j++) {
      const int n = q0 + wave * 16 + lq * 4 + j;
      pl[((size_t)((sp * B_ + b) * H_) + h) * N_ + n] = lacc[j];
    }
  }
  #pragma unroll
  for (int di = 0; di < 4; di++)
    #pragma unroll
    for (int j = 0; j < 4; j++) {
      const int n = q0 + wave * 16 + lq * 4 + j;
      po[((size_t)(b * N_) + n) * 512 + h * D_ + di * 16 + l16] = f2bf(acc[di][j]);
    }
}

extern "C" void kernel_launch(void* const* d_in, const int* in_sizes, int n_in,
                              void* d_out, int out_size, void* d_ws, size_t ws_size,
                              hipStream_t stream) {
  const float* x     = (const float*)d_in[0];
  const float* gamma = (const float*)d_in[1];
  const float* beta  = (const float*)d_in[2];
  const float* w_qkv = (const float*)d_in[3];
  const float* w_out = (const float*)d_in[4];
  const float* b_out = (const float*)d_in[5];
  float* out = (float*)d_out;

  char* ws = (char*)d_ws;
  u16*    po0    = (u16*)(ws + 0);          // 4 partials @ 0,9.44,18.87,28.31 MB
  u16*    xT     = (u16*)(ws + 0);          // aliases po0; dead after gemm_qkv
  u16*    wq_bf  = (u16*)(ws + 9437184);    // aliases po1; dead after gemm_qkv
  u16*    vsec   = (u16*)(ws + 37748736);
  u16*    qT     = (u16*)(ws + 47185920);
  u16*    kT     = (u16*)(ws + 56623104);
  float*  pl     = (float*)(ws + 66060288);
  float2* part   = (float2*)(ws + 67239936);
  u16*    wo_bf  = (u16*)(ws + 67276800);
  float2* scsh   = (float2*)(ws + 67801088);

  prep_all<<<dim3(1408), dim3(256), 0, stream>>>(w_qkv, w_out, wq_bf, wo_bf, x, xT, part);
  make_scsh<<<dim3(B_), dim3(512), 0, stream>>>(part, gamma, beta, scsh);
  gemm_qkv<<<dim3(6, 18, B_), dim3(512), 0, stream>>>(wq_bf, xT, scsh, qT, kT, vsec);
  attn_kernel23<<<dim3(H_, N_ / 128, B_ * SPLIT), dim3(512), 0, stream>>>(qT, kT, vsec, po0, pl);
  gemm_out_fused<<<dim3(4, 18, B_), dim3(256), 0, stream>>>(po0, wo_bf, pl, out, b_out);
}

// Round 24
// 121.647 us; speedup vs baseline: 1.1482x; 1.1482x over previous
//
#include <hip/hip_runtime.h>
#include <hip/hip_bf16.h>

// SelfAttention fused pipeline, bf16 MFMA path, K-split flash attention.
// x[4,512,48,48] -> GN(32) -> qkv 1x1 conv -> 8-head attn (N=2304,D=64) -> out proj.
// GN folded as per-channel affine into gemm_qkv's B staging (single x pass);
// final-norm (po0+po1)/l fused into the out-proj GEMM's B staging; l computed
// via ones-MFMA (no VALU reduction, no epilogue shuffles).
//
// ws layout (67.23 MB < 68.16 MB proven safe):
//   xT    [4][2304][512] bf16 @ 0          (RAW x cast+transpose; dead after gemm_qkv)
//   wq_bf [1536][512] bf16    @ 9437184
//   po0   [4][2304][512] bf16 @ 11010048   (unnormalized partial O, split 0)
//   po1   [4][2304][512] bf16 @ 20447232   (split 1)
//   vsec  [4][512][2304] bf16 @ 37748736   (d-major, n-PERMUTED per 64-group)
//   qT    [4][8][2304][64] bf16 @ 47185920 (QSCALE folded at cast)
//   kT    [4][8][2304][64] bf16 @ 56623104
//   pl    [2][4][8][2304] f32  @ 66060288
//   part  [4][32][36] float2   @ 66650112  (GN partial sums per n-tile)
//   wo_bf [512][512] bf16      @ 66686976
//   scsh  [4][512] float2      @ 67211264  (GN affine: xn = x*sc + sh)

typedef unsigned short u16;
typedef unsigned int u32;
typedef __attribute__((ext_vector_type(8))) short bf16x8;
typedef __attribute__((ext_vector_type(4))) float f32x4;
typedef __attribute__((ext_vector_type(8))) unsigned short us8;
typedef __attribute__((ext_vector_type(4))) unsigned short us4;

#define B_ 4
#define C_ 512
#define N_ 2304
#define H_ 8
#define D_ 64
#define G_ 32
#define SPLIT 2
#define NT (N_ / 64 / SPLIT)   // 18 k-tiles per split block

// log2(e)/8: folded into W_q at cast so QK^T lands in exp2 domain.
#define QSCALE 0.1803368801111204f
// No max subtraction: exp2-domain scores |s| <~ 12, exp2(s) <= ~4096 fits f32/bf16;
// softmax is shift-invariant.

__device__ __forceinline__ u16 f2bf(float f) {
  unsigned u = __float_as_uint(f);
  u += 0x7FFFu + ((u >> 16) & 1u);   // RNE
  return (u16)(u >> 16);
}
__device__ __forceinline__ float bf2f(u16 h) {
  return __uint_as_float(((unsigned)h) << 16);
}
__device__ __forceinline__ u32 pack2bf(float lo, float hi) {
  __hip_bfloat162 t = __float22bfloat162_rn(float2{lo, hi});
  u32 r;
  __builtin_memcpy(&r, &t, 4);
  return r;
}

// async global->LDS, 16B per lane. LDS dest = wave-uniform base + lane*16.
__device__ __forceinline__ void gload16(const void* g, void* l) {
  __builtin_amdgcn_global_load_lds(
      reinterpret_cast<const __attribute__((address_space(1))) unsigned int*>(
          reinterpret_cast<unsigned long long>(g)),
      reinterpret_cast<__attribute__((address_space(3))) unsigned int*>(
          static_cast<unsigned int>(reinterpret_cast<unsigned long long>(l))),
      16, 0, 0);
}

// ---------------- prep: weight cast (blocks 0-255) + x cast/transpose + GN partials ----------------
__global__ __launch_bounds__(256) void prep_all(
    const float* __restrict__ wq, const float* __restrict__ wo,
    u16* __restrict__ wq_bf, u16* __restrict__ wo_bf,
    const float* __restrict__ x, u16* __restrict__ xT, float2* __restrict__ part) {
  if (blockIdx.x < 256) {
    const int n1 = 1536 * 512 / 4, n2 = 512 * 512 / 4;
    const int nq = 512 * 512 / 4;   // q section in float4 units
    for (int i = blockIdx.x * 256 + threadIdx.x; i < n1 + n2; i += 256 * 256) {
      const float4 v = (i < n1) ? ((const float4*)wq)[i] : ((const float4*)wo)[i - n1];
      const float sc = (i < nq) ? QSCALE : 1.0f;
      us4 o; o[0] = f2bf(v.x * sc); o[1] = f2bf(v.y * sc); o[2] = f2bf(v.z * sc); o[3] = f2bf(v.w * sc);
      if (i < n1) ((us4*)wq_bf)[i] = o; else ((us4*)wo_bf)[i - n1] = o;
    }
    return;
  }
  __shared__ u16 T[64][72];
  const int bid = blockIdx.x - 256;            // 0..1151
  const int b = bid / 288, rem = bid % 288;
  const int c0 = (rem & 7) * 64, ni = rem >> 3;   // ni = n-tile 0..35
  const int n0 = ni * 64;
  const int tid = threadIdx.x;
  const int r = tid >> 2, ch = (tid & 3) * 16;
  const float* src = x + (size_t)(b * C_ + c0 + r) * N_ + n0 + ch;
  float s = 0.f, s2 = 0.f;
  #pragma unroll
  for (int j = 0; j < 16; j += 4) {
    const float4 v = *(const float4*)(src + j);
    s  += v.x + v.y + v.z + v.w;
    s2 += v.x * v.x + v.y * v.y + v.z * v.z + v.w * v.w;
    us4 o; o[0] = f2bf(v.x); o[1] = f2bf(v.y); o[2] = f2bf(v.z); o[3] = f2bf(v.w);
    *(us4*)&T[r][ch + j] = o;
  }
  // wave w = c-rows 16w..16w+15 = one group quarter; reduce across 64 lanes
  #pragma unroll
  for (int off = 32; off; off >>= 1) { s += __shfl_xor(s, off); s2 += __shfl_xor(s2, off); }
  if ((tid & 63) == 0) {
    const int g = (c0 >> 4) + (tid >> 6);
    part[((size_t)(b * G_) + g) * 36 + ni] = make_float2(s, s2);
  }
  __syncthreads();
  us8 o1, o2;
  #pragma unroll
  for (int j = 0; j < 8; j++) { o1[j] = T[ch + j][r]; o2[j] = T[ch + 8 + j][r]; }
  u16* dst = xT + (size_t)(b * N_ + n0 + r) * C_ + c0 + ch;
  *(us8*)dst = o1;
  *(us8*)(dst + 8) = o2;
}

// ---------------- finalize GN stats -> scsh[b][c] = (sc, sh) ----------------
__global__ __launch_bounds__(512) void make_scsh(
    const float2* __restrict__ part, const float* __restrict__ gamma,
    const float* __restrict__ beta, float2* __restrict__ scsh) {
  const int b = blockIdx.x, c = threadIdx.x;
  const float2* pp = part + (size_t)(b * G_ + (c >> 4)) * 36;
  float S = 0.f, S2 = 0.f;
  #pragma unroll 4
  for (int i = 0; i < 36; i++) { S += pp[i].x; S2 += pp[i].y; }
  const float inv = 1.f / (16.f * N_);
  const float mean = S * inv;
  const float rstd = rsqrtf(S2 * inv - mean * mean + 1e-5f);
  const float sc = rstd * gamma[c];
  scsh[b * C_ + c] = make_float2(sc, beta[c] - mean * sc);
}

// ---------------- QKV GEMM: 256x128 tile, BK=64, GN affine fused in B staging ----------------
__global__ __launch_bounds__(512) void gemm_qkv(
    const u16* __restrict__ A, const u16* __restrict__ xT,
    const float2* __restrict__ scsh,
    u16* __restrict__ qT, u16* __restrict__ kT, u16* __restrict__ vout) {
  __shared__ u16 As[256][64];
  __shared__ u16 Bs[128][64];
  const int tid = threadIdx.x;
  const int wave = tid >> 6, lane = tid & 63;
  const int l16 = lane & 15, lq = lane >> 4;

  // XCD-chunked bijective block swizzle over grid (6,18,4) = 432 (432%8==0).
  const int lin = blockIdx.x + 6 * (blockIdx.y + 18 * blockIdx.z);
  const int per = 432 >> 3;
  const int eff = (lin & 7) * per + (lin >> 3);
  const int m0 = (eff % 6) * 256;
  const int n0 = ((eff / 6) % 18) * 128;
  const int bz = eff / 108;

  const int wm = (wave >> 1) * 64, wn = (wave & 1) * 64;
  const u16* Bb = xT + (size_t)bz * N_ * C_;
  const float2* sb = scsh + bz * C_;

  f32x4 acc[4][4];
  #pragma unroll
  for (int mi = 0; mi < 4; mi++)
    #pragma unroll
    for (int ni = 0; ni < 4; ni++) {
      acc[mi][ni][0] = 0.f; acc[mi][ni][1] = 0.f; acc[mi][ni][2] = 0.f; acc[mi][ni][3] = 0.f;
    }

  const int h3r = lane >> 3;                 // row-within-8 this lane covers
  const int scg = ((lane & 7) ^ h3r) * 8;    // pre-swizzled global chunk (A)
  const int rdx = l16 & 7;                   // read-side XOR key
  for (int kt = 0; kt < C_; kt += 64) {
    __syncthreads();
    #pragma unroll
    for (int j = 0; j < 4; j++) {
      const int row = wave * 8 + j * 64 + h3r;   // (row & 7) == h3r
      gload16(&A[(size_t)(m0 + row) * C_ + kt + scg], &As[wave * 8 + j * 64][0]);
    }
    // B staging: raw xT us8 (linear chunk) -> GN affine -> swizzled ds_write
    {
      const int cbase = kt + (lane & 7) * 8;
      float2 sv[8];
      #pragma unroll
      for (int e = 0; e < 8; e++) sv[e] = sb[cbase + e];
      #pragma unroll
      for (int j = 0; j < 2; j++) {
        const int row = wave * 8 + j * 64 + h3r;
        const us8 xr = *(const us8*)&Bb[(size_t)(n0 + row) * C_ + cbase];
        us8 o;
        #pragma unroll
        for (int e = 0; e < 8; e++) o[e] = f2bf(bf2f(xr[e]) * sv[e].x + sv[e].y);
        *(us8*)&Bs[row][((lane & 7) ^ h3r) * 8] = o;
      }
    }
    __syncthreads();
    #pragma unroll
    for (int kk = 0; kk < 2; kk++) {
      bf16x8 af[4], bfr[4];
      #pragma unroll
      for (int mi = 0; mi < 4; mi++)
        af[mi] = *(const bf16x8*)&As[wm + mi * 16 + l16][(((kk << 2) | lq) ^ rdx) * 8];
      #pragma unroll
      for (int ni = 0; ni < 4; ni++)
        bfr[ni] = *(const bf16x8*)&Bs[wn + ni * 16 + l16][(((kk << 2) | lq) ^ rdx) * 8];
      #pragma unroll
      for (int mi = 0; mi < 4; mi++)
        #pragma unroll
        for (int ni = 0; ni < 4; ni++)
          acc[mi][ni] = __builtin_amdgcn_mfma_f32_16x16x32_bf16(af[mi], bfr[ni], acc[mi][ni], 0, 0, 0);
    }
  }
  #pragma unroll
  for (int mi = 0; mi < 4; mi++) {
    const int row0 = m0 + wm + mi * 16 + lq * 4;
    #pragma unroll
    for (int ni = 0; ni < 4; ni++) {
      const int col = n0 + wn + ni * 16 + l16;
      const int which = row0 >> 9;           // 0=q, 1=k, 2=v
      if (which < 2) {
        const int h = (row0 >> 6) & 7, d0 = row0 & 63;
        u16* dst = which ? kT : qT;
        us4 o;
        #pragma unroll
        for (int j = 0; j < 4; j++) o[j] = f2bf(acc[mi][ni][j]);
        *(us4*)&dst[((size_t)((bz * H_ + h) * N_) + col) * D_ + d0] = o;
      } else {
        // n-permute within 64-group: n = g32 + hi*16 + lq2*4 + j -> g32 + lq2*8 + hi*4 + j
        const int cp = (col & ~63) | (col & 32) | (((col >> 2) & 3) << 3) |
                       (((col >> 4) & 1) << 2) | (col & 3);
        #pragma unroll
        for (int j = 0; j < 4; j++)
          vout[((size_t)(bz * 512) + (row0 & 511) + j) * N_ + cp] = f2bf(acc[mi][ni][j]);
      }
    }
  }
}

// ---------------- out-proj GEMM with fused combine: B = (po0+po1)*rl staged in-kernel ----------------
__global__ __launch_bounds__(256) void gemm_out_fused(
    const u16* __restrict__ A, const u16* __restrict__ po0, const u16* __restrict__ po1,
    const float* __restrict__ pl, float* __restrict__ C, const float* __restrict__ bias) {
  __shared__ u16 As[128][64];
  __shared__ u16 Bs[128][64];
  const int tid = threadIdx.x;
  const int wave = tid >> 6, lane = tid & 63;
  const int l16 = lane & 15, lq = lane >> 4;

  // XCD-chunked bijective swizzle over grid (4,18,4) = 288 (288%8==0).
  const int lin = blockIdx.x + 4 * (blockIdx.y + 18 * blockIdx.z);
  const int per = 288 >> 3;
  const int eff = (lin & 7) * per + (lin >> 3);
  const int m0 = (eff % 4) * 128;
  const int n0 = ((eff / 4) % 18) * 128;
  const int bz = eff / 72;

  const int wm = (wave >> 1) * 64, wn = (wave & 1) * 64;

  f32x4 acc[4][4];
  #pragma unroll
  for (int mi = 0; mi < 4; mi++)
    #pragma unroll
    for (int ni = 0; ni < 4; ni++) {
      acc[mi][ni][0] = 0.f; acc[mi][ni][1] = 0.f; acc[mi][ni][2] = 0.f; acc[mi][ni][3] = 0.f;
    }

  const int h3r = lane >> 3;
  const int scg = ((lane & 7) ^ h3r) * 8;
  const int rdx = l16 & 7;
  const size_t lstr = (size_t)B_ * H_ * N_;
  for (int kt = 0; kt < C_; kt += 64) {
    __syncthreads();
    #pragma unroll
    for (int j = 0; j < 4; j++) {
      const int row = wave * 8 + j * 32 + h3r;
      gload16(&A[(size_t)(m0 + row) * C_ + kt + scg], &As[wave * 8 + j * 32][0]);
    }
    #pragma unroll
    for (int j = 0; j < 4; j++) {
      const int row = wave * 8 + j * 32 + h3r;
      const size_t pbase = ((size_t)(bz * N_) + n0 + row) * 512 + kt + (lane & 7) * 8;
      const us8 a = *(const us8*)&po0[pbase];
      const us8 c2 = *(const us8*)&po1[pbase];
      const size_t lidx = ((size_t)(bz * H_) + (kt >> 6)) * N_ + n0 + row;
      const float rl = 1.0f / (pl[lidx] + pl[lidx + lstr]);
      us8 o;
      #pragma unroll
      for (int e = 0; e < 8; e++) o[e] = f2bf((bf2f(a[e]) + bf2f(c2[e])) * rl);
      *(us8*)&Bs[row][((lane & 7) ^ h3r) * 8] = o;
    }
    __syncthreads();
    #pragma unroll
    for (int kk = 0; kk < 2; kk++) {
      bf16x8 af[4], bfr[4];
      #pragma unroll
      for (int mi = 0; mi < 4; mi++)
        af[mi] = *(const bf16x8*)&As[wm + mi * 16 + l16][(((kk << 2) | lq) ^ rdx) * 8];
      #pragma unroll
      for (int ni = 0; ni < 4; ni++)
        bfr[ni] = *(const bf16x8*)&Bs[wn + ni * 16 + l16][(((kk << 2) | lq) ^ rdx) * 8];
      #pragma unroll
      for (int mi = 0; mi < 4; mi++)
        #pragma unroll
        for (int ni = 0; ni < 4; ni++)
          acc[mi][ni] = __builtin_amdgcn_mfma_f32_16x16x32_bf16(af[mi], bfr[ni], acc[mi][ni], 0, 0, 0);
    }
  }
  #pragma unroll
  for (int mi = 0; mi < 4; mi++) {
    const int row0 = m0 + wm + mi * 16 + lq * 4;
    #pragma unroll
    for (int ni = 0; ni < 4; ni++) {
      const int col = n0 + wn + ni * 16 + l16;
      #pragma unroll
      for (int j = 0; j < 4; j++) {
        const size_t idx = ((size_t)bz * C_ + row0 + j) * N_ + col;
        C[idx] = acc[mi][ni][j] + bias[row0 + j];
      }
    }
  }
}

// ---------------- flash attention v24: SPLIT=2 + l via ones-MFMA ----------------
// block = (h, q-tile of 128, b*SPLIT+sp), 8 waves x 16 q-rows, 18 k-tiles.
// l computed by one extra MFMA per kh with an all-ones B-operand (sums p over
// all 32 k-slots incl. cross-lane) -> no VALU l-sum, no epilogue shuffles.
__global__ __launch_bounds__(512) void attn_kernel24(
    const u16* __restrict__ qT, const u16* __restrict__ kT,
    const u16* __restrict__ vp, u16* __restrict__ po0,
    float* __restrict__ pl) {
  __shared__ u16 Ks[2][64][64];
  __shared__ u16 Vs[2][64][64];

  const int h = blockIdx.x;
  const int b = blockIdx.z >> 1, sp = blockIdx.z & 1;
  const int q0 = blockIdx.y * 128;
  const int tid = threadIdx.x;
  const int wave = tid >> 6, lane = tid & 63;
  const int l16 = lane & 15, lq = lane >> 4;
  const int h3 = l16 & 7;                  // read-side XOR key
  const int kt0 = sp * NT;

  bf16x8 qf[2];
  {
    const u16* qb = qT + ((size_t)((b * H_ + h) * N_ + q0 + wave * 16 + l16)) * D_;
    qf[0] = *(const bf16x8*)(qb + lq * 8);
    qf[1] = *(const bf16x8*)(qb + 32 + lq * 8);
  }

  f32x4 acc[4], lacc;
  #pragma unroll
  for (int di = 0; di < 4; di++) {
    acc[di][0] = 0.f; acc[di][1] = 0.f; acc[di][2] = 0.f; acc[di][3] = 0.f;
  }
  lacc[0] = 0.f; lacc[1] = 0.f; lacc[2] = 0.f; lacc[3] = 0.f;
  const f32x4 z4 = {0.f, 0.f, 0.f, 0.f};
  union { u32 w[4]; bf16x8 v; } ones;
  ones.w[0] = 0x3F803F80u; ones.w[1] = 0x3F803F80u;
  ones.w[2] = 0x3F803F80u; ones.w[3] = 0x3F803F80u;

  const u16* kbase = kT + (size_t)(b * H_ + h) * N_ * D_;
  const u16* vbase = vp + ((size_t)(b * 512) + h * D_) * N_;
  const int srow = wave * 8 + (lane >> 3);
  const int scg  = (((lane & 7) ^ (srow & 7))) * 8;

  gload16(&kbase[(size_t)(kt0 * 64 + srow) * D_ + scg], &Ks[0][wave * 8][0]);
  gload16(&vbase[(size_t)srow * N_ + kt0 * 64 + scg],   &Vs[0][wave * 8][0]);

  int cur = 0;
  for (int t = 0; t < NT; t++) {
    const int kt = kt0 + t;
    __syncthreads();

    if (t + 1 < NT) {
      gload16(&kbase[(size_t)((kt + 1) * 64 + srow) * D_ + scg], &Ks[cur ^ 1][wave * 8][0]);
      gload16(&vbase[(size_t)srow * N_ + (kt + 1) * 64 + scg],   &Vs[cur ^ 1][wave * 8][0]);
    }

    // ---- S^T = K Q^T ----
    f32x4 s[4];
    __builtin_amdgcn_s_setprio(1);
    #pragma unroll
    for (int ni = 0; ni < 4; ni++) {
      const bf16x8 k0 = *(const bf16x8*)&Ks[cur][ni * 16 + l16][(lq ^ h3) * 8];
      const bf16x8 k1 = *(const bf16x8*)&Ks[cur][ni * 16 + l16][((4 | lq) ^ h3) * 8];
      s[ni] = __builtin_amdgcn_mfma_f32_16x16x32_bf16(k0, qf[0], z4, 0, 0, 0);
      s[ni] = __builtin_amdgcn_mfma_f32_16x16x32_bf16(k1, qf[1], s[ni], 0, 0, 0);
    }
    __builtin_amdgcn_s_setprio(0);

    // ---- p = exp2(s); pack directly into PV a-frag words (no VALU l-sum) ----
    union { u32 w[4]; bf16x8 v; } af[2];
    #pragma unroll
    for (int ni = 0; ni < 4; ni++) {
      const float p0 = __builtin_amdgcn_exp2f(s[ni][0]);
      const float p1 = __builtin_amdgcn_exp2f(s[ni][1]);
      const float p2 = __builtin_amdgcn_exp2f(s[ni][2]);
      const float p3 = __builtin_amdgcn_exp2f(s[ni][3]);
      af[ni >> 1].w[(ni & 1) * 2]     = pack2bf(p0, p1);
      af[ni >> 1].w[(ni & 1) * 2 + 1] = pack2bf(p2, p3);
    }

    // ---- PV + l (ones-MFMA sums p over all k-slots incl. cross-lane) ----
    __builtin_amdgcn_s_setprio(1);
    #pragma unroll
    for (int kh = 0; kh < 2; kh++) {
      lacc = __builtin_amdgcn_mfma_f32_16x16x32_bf16(af[kh].v, ones.v, lacc, 0, 0, 0);
      #pragma unroll
      for (int di = 0; di < 4; di++) {
        const bf16x8 vf = *(const bf16x8*)&Vs[cur][di * 16 + l16][(((kh << 2) | lq) ^ h3) * 8];
        acc[di] = __builtin_amdgcn_mfma_f32_16x16x32_bf16(af[kh].v, vf, acc[di], 0, 0, 0);
      }
    }
    __builtin_amdgcn_s_setprio(0);

    cur ^= 1;
  }

  // ---- epilogue: write unnormalized partial O (bf16) + partial l ----
  u16* po = po0 + (size_t)sp * ((size_t)B_ * N_ * 512);
  if (l16 == 0) {
    #pragma unroll
    for (int j = 0; j < 4; j++) {
      const int n = q0 + wave * 16 + lq * 4 + j;
      pl[((size_t)((sp * B_ + b) * H_) + h) * N_ + n] = lacc[j];
    }
  }
  #pragma unroll
  for (int di = 0; di < 4; di++)
    #pragma unroll
    for (int j = 0; j < 4; j++) {
      const int n = q0 + wave * 16 + lq * 4 + j;
      po[((size_t)(b * N_) + n) * 512 + h * D_ + di * 16 + l16] = f2bf(acc[di][j]);
    }
}

extern "C" void kernel_launch(void* const* d_in, const int* in_sizes, int n_in,
                              void* d_out, int out_size, void* d_ws, size_t ws_size,
                              hipStream_t stream) {
  const float* x     = (const float*)d_in[0];
  const float* gamma = (const float*)d_in[1];
  const float* beta  = (const float*)d_in[2];
  const float* w_qkv = (const float*)d_in[3];
  const float* w_out = (const float*)d_in[4];
  const float* b_out = (const float*)d_in[5];
  float* out = (float*)d_out;

  char* ws = (char*)d_ws;
  u16*    xT     = (u16*)(ws + 0);          // dead after gemm_qkv
  u16*    wq_bf  = (u16*)(ws + 9437184);
  u16*    po0    = (u16*)(ws + 11010048);
  u16*    po1    = (u16*)(ws + 20447232);
  u16*    vsec   = (u16*)(ws + 37748736);
  u16*    qT     = (u16*)(ws + 47185920);
  u16*    kT     = (u16*)(ws + 56623104);
  float*  pl     = (float*)(ws + 66060288);
  float2* part   = (float2*)(ws + 66650112);
  u16*    wo_bf  = (u16*)(ws + 66686976);
  float2* scsh   = (float2*)(ws + 67211264);

  prep_all<<<dim3(1408), dim3(256), 0, stream>>>(w_qkv, w_out, wq_bf, wo_bf, x, xT, part);
  make_scsh<<<dim3(B_), dim3(512), 0, stream>>>(part, gamma, beta, scsh);
  gemm_qkv<<<dim3(6, 18, B_), dim3(512), 0, stream>>>(wq_bf, xT, scsh, qT, kT, vsec);
  attn_kernel24<<<dim3(H_, N_ / 128, B_ * SPLIT), dim3(512), 0, stream>>>(qT, kT, vsec, po0, pl);
  gemm_out_fused<<<dim3(4, 18, B_), dim3(256), 0, stream>>>(wo_bf, po0, po1, pl, out, b_out);
}

// Round 25
// 118.045 us; speedup vs baseline: 1.1833x; 1.0305x over previous
//
#include <hip/hip_runtime.h>
#include <hip/hip_bf16.h>

// SelfAttention fused pipeline, bf16 MFMA path, K-split flash attention.
// x[4,512,48,48] -> GN(32) -> qkv 1x1 conv -> 8-head attn (N=2304,D=64) -> out proj.
// GN folded as per-channel affine into gemm_qkv's B staging (single x pass);
// final-norm (po0+po1)/l fused into the out-proj GEMM's B staging; l computed
// via ones-MFMA. Out-proj uses the 256x128/512-thread tile (po traffic halved).
//
// ws layout (67.23 MB < 68.16 MB proven safe):
//   xT    [4][2304][512] bf16 @ 0          (RAW x cast+transpose; dead after gemm_qkv)
//   wq_bf [1536][512] bf16    @ 9437184
//   po0   [4][2304][512] bf16 @ 11010048   (unnormalized partial O, split 0)
//   po1   [4][2304][512] bf16 @ 20447232   (split 1)
//   vsec  [4][512][2304] bf16 @ 37748736   (d-major, n-PERMUTED per 64-group)
//   qT    [4][8][2304][64] bf16 @ 47185920 (QSCALE folded at cast)
//   kT    [4][8][2304][64] bf16 @ 56623104
//   pl    [2][4][8][2304] f32  @ 66060288
//   part  [4][32][36] float2   @ 66650112  (GN partial sums per n-tile)
//   wo_bf [512][512] bf16      @ 66686976
//   scsh  [4][512] float2      @ 67211264  (GN affine: xn = x*sc + sh)

typedef unsigned short u16;
typedef unsigned int u32;
typedef __attribute__((ext_vector_type(8))) short bf16x8;
typedef __attribute__((ext_vector_type(4))) float f32x4;
typedef __attribute__((ext_vector_type(8))) unsigned short us8;
typedef __attribute__((ext_vector_type(4))) unsigned short us4;

#define B_ 4
#define C_ 512
#define N_ 2304
#define H_ 8
#define D_ 64
#define G_ 32
#define SPLIT 2
#define NT (N_ / 64 / SPLIT)   // 18 k-tiles per split block

// log2(e)/8: folded into W_q at cast so QK^T lands in exp2 domain.
#define QSCALE 0.1803368801111204f
// No max subtraction: exp2-domain scores |s| <~ 12, exp2(s) <= ~4096 fits f32/bf16;
// softmax is shift-invariant.

__device__ __forceinline__ u16 f2bf(float f) {
  unsigned u = __float_as_uint(f);
  u += 0x7FFFu + ((u >> 16) & 1u);   // RNE
  return (u16)(u >> 16);
}
__device__ __forceinline__ float bf2f(u16 h) {
  return __uint_as_float(((unsigned)h) << 16);
}
__device__ __forceinline__ u32 pack2bf(float lo, float hi) {
  __hip_bfloat162 t = __float22bfloat162_rn(float2{lo, hi});
  u32 r;
  __builtin_memcpy(&r, &t, 4);
  return r;
}

// async global->LDS, 16B per lane. LDS dest = wave-uniform base + lane*16.
__device__ __forceinline__ void gload16(const void* g, void* l) {
  __builtin_amdgcn_global_load_lds(
      reinterpret_cast<const __attribute__((address_space(1))) unsigned int*>(
          reinterpret_cast<unsigned long long>(g)),
      reinterpret_cast<__attribute__((address_space(3))) unsigned int*>(
          static_cast<unsigned int>(reinterpret_cast<unsigned long long>(l))),
      16, 0, 0);
}

// ---------------- prep: weight cast (blocks 0-255) + x cast/transpose + GN partials ----------------
__global__ __launch_bounds__(256) void prep_all(
    const float* __restrict__ wq, const float* __restrict__ wo,
    u16* __restrict__ wq_bf, u16* __restrict__ wo_bf,
    const float* __restrict__ x, u16* __restrict__ xT, float2* __restrict__ part) {
  if (blockIdx.x < 256) {
    const int n1 = 1536 * 512 / 4, n2 = 512 * 512 / 4;
    const int nq = 512 * 512 / 4;   // q section in float4 units
    for (int i = blockIdx.x * 256 + threadIdx.x; i < n1 + n2; i += 256 * 256) {
      const float4 v = (i < n1) ? ((const float4*)wq)[i] : ((const float4*)wo)[i - n1];
      const float sc = (i < nq) ? QSCALE : 1.0f;
      us4 o; o[0] = f2bf(v.x * sc); o[1] = f2bf(v.y * sc); o[2] = f2bf(v.z * sc); o[3] = f2bf(v.w * sc);
      if (i < n1) ((us4*)wq_bf)[i] = o; else ((us4*)wo_bf)[i - n1] = o;
    }
    return;
  }
  __shared__ u16 T[64][72];
  const int bid = blockIdx.x - 256;            // 0..1151
  const int b = bid / 288, rem = bid % 288;
  const int c0 = (rem & 7) * 64, ni = rem >> 3;   // ni = n-tile 0..35
  const int n0 = ni * 64;
  const int tid = threadIdx.x;
  const int r = tid >> 2, ch = (tid & 3) * 16;
  const float* src = x + (size_t)(b * C_ + c0 + r) * N_ + n0 + ch;
  float s = 0.f, s2 = 0.f;
  #pragma unroll
  for (int j = 0; j < 16; j += 4) {
    const float4 v = *(const float4*)(src + j);
    s  += v.x + v.y + v.z + v.w;
    s2 += v.x * v.x + v.y * v.y + v.z * v.z + v.w * v.w;
    us4 o; o[0] = f2bf(v.x); o[1] = f2bf(v.y); o[2] = f2bf(v.z); o[3] = f2bf(v.w);
    *(us4*)&T[r][ch + j] = o;
  }
  // wave w = c-rows 16w..16w+15 = one group quarter; reduce across 64 lanes
  #pragma unroll
  for (int off = 32; off; off >>= 1) { s += __shfl_xor(s, off); s2 += __shfl_xor(s2, off); }
  if ((tid & 63) == 0) {
    const int g = (c0 >> 4) + (tid >> 6);
    part[((size_t)(b * G_) + g) * 36 + ni] = make_float2(s, s2);
  }
  __syncthreads();
  us8 o1, o2;
  #pragma unroll
  for (int j = 0; j < 8; j++) { o1[j] = T[ch + j][r]; o2[j] = T[ch + 8 + j][r]; }
  u16* dst = xT + (size_t)(b * N_ + n0 + r) * C_ + c0 + ch;
  *(us8*)dst = o1;
  *(us8*)(dst + 8) = o2;
}

// ---------------- finalize GN stats -> scsh[b][c] = (sc, sh) ----------------
__global__ __launch_bounds__(512) void make_scsh(
    const float2* __restrict__ part, const float* __restrict__ gamma,
    const float* __restrict__ beta, float2* __restrict__ scsh) {
  const int b = blockIdx.x, c = threadIdx.x;
  const float2* pp = part + (size_t)(b * G_ + (c >> 4)) * 36;
  float S = 0.f, S2 = 0.f;
  #pragma unroll 4
  for (int i = 0; i < 36; i++) { S += pp[i].x; S2 += pp[i].y; }
  const float inv = 1.f / (16.f * N_);
  const float mean = S * inv;
  const float rstd = rsqrtf(S2 * inv - mean * mean + 1e-5f);
  const float sc = rstd * gamma[c];
  scsh[b * C_ + c] = make_float2(sc, beta[c] - mean * sc);
}

// ---------------- QKV GEMM: 256x128 tile, BK=64, GN affine fused in B staging ----------------
__global__ __launch_bounds__(512) void gemm_qkv(
    const u16* __restrict__ A, const u16* __restrict__ xT,
    const float2* __restrict__ scsh,
    u16* __restrict__ qT, u16* __restrict__ kT, u16* __restrict__ vout) {
  __shared__ u16 As[256][64];
  __shared__ u16 Bs[128][64];
  const int tid = threadIdx.x;
  const int wave = tid >> 6, lane = tid & 63;
  const int l16 = lane & 15, lq = lane >> 4;

  // XCD-chunked bijective block swizzle over grid (6,18,4) = 432 (432%8==0).
  const int lin = blockIdx.x + 6 * (blockIdx.y + 18 * blockIdx.z);
  const int per = 432 >> 3;
  const int eff = (lin & 7) * per + (lin >> 3);
  const int m0 = (eff % 6) * 256;
  const int n0 = ((eff / 6) % 18) * 128;
  const int bz = eff / 108;

  const int wm = (wave >> 1) * 64, wn = (wave & 1) * 64;
  const u16* Bb = xT + (size_t)bz * N_ * C_;
  const float2* sb = scsh + bz * C_;

  f32x4 acc[4][4];
  #pragma unroll
  for (int mi = 0; mi < 4; mi++)
    #pragma unroll
    for (int ni = 0; ni < 4; ni++) {
      acc[mi][ni][0] = 0.f; acc[mi][ni][1] = 0.f; acc[mi][ni][2] = 0.f; acc[mi][ni][3] = 0.f;
    }

  const int h3r = lane >> 3;                 // row-within-8 this lane covers
  const int scg = ((lane & 7) ^ h3r) * 8;    // pre-swizzled global chunk (A)
  const int rdx = l16 & 7;                   // read-side XOR key
  for (int kt = 0; kt < C_; kt += 64) {
    __syncthreads();
    #pragma unroll
    for (int j = 0; j < 4; j++) {
      const int row = wave * 8 + j * 64 + h3r;   // (row & 7) == h3r
      gload16(&A[(size_t)(m0 + row) * C_ + kt + scg], &As[wave * 8 + j * 64][0]);
    }
    // B staging: raw xT us8 (linear chunk) -> GN affine -> swizzled ds_write
    {
      const int cbase = kt + (lane & 7) * 8;
      float2 sv[8];
      #pragma unroll
      for (int e = 0; e < 8; e++) sv[e] = sb[cbase + e];
      #pragma unroll
      for (int j = 0; j < 2; j++) {
        const int row = wave * 8 + j * 64 + h3r;
        const us8 xr = *(const us8*)&Bb[(size_t)(n0 + row) * C_ + cbase];
        us8 o;
        #pragma unroll
        for (int e = 0; e < 8; e++) o[e] = f2bf(bf2f(xr[e]) * sv[e].x + sv[e].y);
        *(us8*)&Bs[row][((lane & 7) ^ h3r) * 8] = o;
      }
    }
    __syncthreads();
    #pragma unroll
    for (int kk = 0; kk < 2; kk++) {
      bf16x8 af[4], bfr[4];
      #pragma unroll
      for (int mi = 0; mi < 4; mi++)
        af[mi] = *(const bf16x8*)&As[wm + mi * 16 + l16][(((kk << 2) | lq) ^ rdx) * 8];
      #pragma unroll
      for (int ni = 0; ni < 4; ni++)
        bfr[ni] = *(const bf16x8*)&Bs[wn + ni * 16 + l16][(((kk << 2) | lq) ^ rdx) * 8];
      #pragma unroll
      for (int mi = 0; mi < 4; mi++)
        #pragma unroll
        for (int ni = 0; ni < 4; ni++)
          acc[mi][ni] = __builtin_amdgcn_mfma_f32_16x16x32_bf16(af[mi], bfr[ni], acc[mi][ni], 0, 0, 0);
    }
  }
  #pragma unroll
  for (int mi = 0; mi < 4; mi++) {
    const int row0 = m0 + wm + mi * 16 + lq * 4;
    #pragma unroll
    for (int ni = 0; ni < 4; ni++) {
      const int col = n0 + wn + ni * 16 + l16;
      const int which = row0 >> 9;           // 0=q, 1=k, 2=v
      if (which < 2) {
        const int h = (row0 >> 6) & 7, d0 = row0 & 63;
        u16* dst = which ? kT : qT;
        us4 o;
        #pragma unroll
        for (int j = 0; j < 4; j++) o[j] = f2bf(acc[mi][ni][j]);
        *(us4*)&dst[((size_t)((bz * H_ + h) * N_) + col) * D_ + d0] = o;
      } else {
        // n-permute within 64-group: n = g32 + hi*16 + lq2*4 + j -> g32 + lq2*8 + hi*4 + j
        const int cp = (col & ~63) | (col & 32) | (((col >> 2) & 3) << 3) |
                       (((col >> 4) & 1) << 2) | (col & 3);
        #pragma unroll
        for (int j = 0; j < 4; j++)
          vout[((size_t)(bz * 512) + (row0 & 511) + j) * N_ + cp] = f2bf(acc[mi][ni][j]);
      }
    }
  }
}

// ---------------- out-proj GEMM, 256x128 tile, 512 threads, fused combine ----------------
// out[bz][m][n] = wo_bf[m][k] * ((po0+po1)[bz][n][k] / l[bz][n]) + bias; f32 out.
// Same geometry as gemm_qkv (As[256][64], 8 waves); grid (2,18,4)=144 -> po read
// halves vs 128-tile (each n-panel staged by 2 m-blocks instead of 4).
__global__ __launch_bounds__(512) void gemm_out_fused(
    const u16* __restrict__ A, const u16* __restrict__ po0, const u16* __restrict__ po1,
    const float* __restrict__ pl, float* __restrict__ C, const float* __restrict__ bias) {
  __shared__ u16 As[256][64];
  __shared__ u16 Bs[128][64];
  const int tid = threadIdx.x;
  const int wave = tid >> 6, lane = tid & 63;
  const int l16 = lane & 15, lq = lane >> 4;

  // XCD-chunked bijective swizzle over grid (2,18,4) = 144 (144%8==0).
  const int lin = blockIdx.x + 2 * (blockIdx.y + 18 * blockIdx.z);
  const int per = 144 >> 3;
  const int eff = (lin & 7) * per + (lin >> 3);
  const int m0 = (eff % 2) * 256;
  const int n0 = ((eff / 2) % 18) * 128;
  const int bz = eff / 36;

  const int wm = (wave >> 1) * 64, wn = (wave & 1) * 64;

  f32x4 acc[4][4];
  #pragma unroll
  for (int mi = 0; mi < 4; mi++)
    #pragma unroll
    for (int ni = 0; ni < 4; ni++) {
      acc[mi][ni][0] = 0.f; acc[mi][ni][1] = 0.f; acc[mi][ni][2] = 0.f; acc[mi][ni][3] = 0.f;
    }

  const int h3r = lane >> 3;                 // row-within-8 this lane covers
  const int scg = ((lane & 7) ^ h3r) * 8;    // pre-swizzled global chunk (A)
  const int rdx = l16 & 7;                   // read-side XOR key
  const size_t lstr = (size_t)B_ * H_ * N_;
  for (int kt = 0; kt < C_; kt += 64) {
    __syncthreads();
    // A staging: global_load_lds, pre-swizzled source (256 rows, 4 issues/wave)
    #pragma unroll
    for (int j = 0; j < 4; j++) {
      const int row = wave * 8 + j * 64 + h3r;
      gload16(&A[(size_t)(m0 + row) * C_ + kt + scg], &As[wave * 8 + j * 64][0]);
    }
    // B staging: reg-staged combine+norm (128 rows, 2 passes/wave)
    #pragma unroll
    for (int j = 0; j < 2; j++) {
      const int row = wave * 8 + j * 64 + h3r;
      const size_t pbase = ((size_t)(bz * N_) + n0 + row) * 512 + kt + (lane & 7) * 8;
      const us8 a = *(const us8*)&po0[pbase];
      const us8 c2 = *(const us8*)&po1[pbase];
      const size_t lidx = ((size_t)(bz * H_) + (kt >> 6)) * N_ + n0 + row;
      const float rl = 1.0f / (pl[lidx] + pl[lidx + lstr]);
      us8 o;
      #pragma unroll
      for (int e = 0; e < 8; e++) o[e] = f2bf((bf2f(a[e]) + bf2f(c2[e])) * rl);
      *(us8*)&Bs[row][((lane & 7) ^ h3r) * 8] = o;
    }
    __syncthreads();
    #pragma unroll
    for (int kk = 0; kk < 2; kk++) {
      bf16x8 af[4], bfr[4];
      #pragma unroll
      for (int mi = 0; mi < 4; mi++)
        af[mi] = *(const bf16x8*)&As[wm + mi * 16 + l16][(((kk << 2) | lq) ^ rdx) * 8];
      #pragma unroll
      for (int ni = 0; ni < 4; ni++)
        bfr[ni] = *(const bf16x8*)&Bs[wn + ni * 16 + l16][(((kk << 2) | lq) ^ rdx) * 8];
      #pragma unroll
      for (int mi = 0; mi < 4; mi++)
        #pragma unroll
        for (int ni = 0; ni < 4; ni++)
          acc[mi][ni] = __builtin_amdgcn_mfma_f32_16x16x32_bf16(af[mi], bfr[ni], acc[mi][ni], 0, 0, 0);
    }
  }
  #pragma unroll
  for (int mi = 0; mi < 4; mi++) {
    const int row0 = m0 + wm + mi * 16 + lq * 4;
    #pragma unroll
    for (int ni = 0; ni < 4; ni++) {
      const int col = n0 + wn + ni * 16 + l16;
      #pragma unroll
      for (int j = 0; j < 4; j++) {
        const size_t idx = ((size_t)bz * C_ + row0 + j) * N_ + col;
        C[idx] = acc[mi][ni][j] + bias[row0 + j];
      }
    }
  }
}

// ---------------- flash attention v24: SPLIT=2 + l via ones-MFMA (unchanged) ----------------
__global__ __launch_bounds__(512) void attn_kernel24(
    const u16* __restrict__ qT, const u16* __restrict__ kT,
    const u16* __restrict__ vp, u16* __restrict__ po0,
    float* __restrict__ pl) {
  __shared__ u16 Ks[2][64][64];
  __shared__ u16 Vs[2][64][64];

  const int h = blockIdx.x;
  const int b = blockIdx.z >> 1, sp = blockIdx.z & 1;
  const int q0 = blockIdx.y * 128;
  const int tid = threadIdx.x;
  const int wave = tid >> 6, lane = tid & 63;
  const int l16 = lane & 15, lq = lane >> 4;
  const int h3 = l16 & 7;                  // read-side XOR key
  const int kt0 = sp * NT;

  bf16x8 qf[2];
  {
    const u16* qb = qT + ((size_t)((b * H_ + h) * N_ + q0 + wave * 16 + l16)) * D_;
    qf[0] = *(const bf16x8*)(qb + lq * 8);
    qf[1] = *(const bf16x8*)(qb + 32 + lq * 8);
  }

  f32x4 acc[4], lacc;
  #pragma unroll
  for (int di = 0; di < 4; di++) {
    acc[di][0] = 0.f; acc[di][1] = 0.f; acc[di][2] = 0.f; acc[di][3] = 0.f;
  }
  lacc[0] = 0.f; lacc[1] = 0.f; lacc[2] = 0.f; lacc[3] = 0.f;
  const f32x4 z4 = {0.f, 0.f, 0.f, 0.f};
  union { u32 w[4]; bf16x8 v; } ones;
  ones.w[0] = 0x3F803F80u; ones.w[1] = 0x3F803F80u;
  ones.w[2] = 0x3F803F80u; ones.w[3] = 0x3F803F80u;

  const u16* kbase = kT + (size_t)(b * H_ + h) * N_ * D_;
  const u16* vbase = vp + ((size_t)(b * 512) + h * D_) * N_;
  const int srow = wave * 8 + (lane >> 3);
  const int scg  = (((lane & 7) ^ (srow & 7))) * 8;

  gload16(&kbase[(size_t)(kt0 * 64 + srow) * D_ + scg], &Ks[0][wave * 8][0]);
  gload16(&vbase[(size_t)srow * N_ + kt0 * 64 + scg],   &Vs[0][wave * 8][0]);

  int cur = 0;
  for (int t = 0; t < NT; t++) {
    const int kt = kt0 + t;
    __syncthreads();

    if (t + 1 < NT) {
      gload16(&kbase[(size_t)((kt + 1) * 64 + srow) * D_ + scg], &Ks[cur ^ 1][wave * 8][0]);
      gload16(&vbase[(size_t)srow * N_ + (kt + 1) * 64 + scg],   &Vs[cur ^ 1][wave * 8][0]);
    }

    // ---- S^T = K Q^T ----
    f32x4 s[4];
    __builtin_amdgcn_s_setprio(1);
    #pragma unroll
    for (int ni = 0; ni < 4; ni++) {
      const bf16x8 k0 = *(const bf16x8*)&Ks[cur][ni * 16 + l16][(lq ^ h3) * 8];
      const bf16x8 k1 = *(const bf16x8*)&Ks[cur][ni * 16 + l16][((4 | lq) ^ h3) * 8];
      s[ni] = __builtin_amdgcn_mfma_f32_16x16x32_bf16(k0, qf[0], z4, 0, 0, 0);
      s[ni] = __builtin_amdgcn_mfma_f32_16x16x32_bf16(k1, qf[1], s[ni], 0, 0, 0);
    }
    __builtin_amdgcn_s_setprio(0);

    // ---- p = exp2(s); pack directly into PV a-frag words (no VALU l-sum) ----
    union { u32 w[4]; bf16x8 v; } af[2];
    #pragma unroll
    for (int ni = 0; ni < 4; ni++) {
      const float p0 = __builtin_amdgcn_exp2f(s[ni][0]);
      const float p1 = __builtin_amdgcn_exp2f(s[ni][1]);
      const float p2 = __builtin_amdgcn_exp2f(s[ni][2]);
      const float p3 = __builtin_amdgcn_exp2f(s[ni][3]);
      af[ni >> 1].w[(ni & 1) * 2]     = pack2bf(p0, p1);
      af[ni >> 1].w[(ni & 1) * 2 + 1] = pack2bf(p2, p3);
    }

    // ---- PV + l (ones-MFMA sums p over all k-slots incl. cross-lane) ----
    __builtin_amdgcn_s_setprio(1);
    #pragma unroll
    for (int kh = 0; kh < 2; kh++) {
      lacc = __builtin_amdgcn_mfma_f32_16x16x32_bf16(af[kh].v, ones.v, lacc, 0, 0, 0);
      #pragma unroll
      for (int di = 0; di < 4; di++) {
        const bf16x8 vf = *(const bf16x8*)&Vs[cur][di * 16 + l16][(((kh << 2) | lq) ^ h3) * 8];
        acc[di] = __builtin_amdgcn_mfma_f32_16x16x32_bf16(af[kh].v, vf, acc[di], 0, 0, 0);
      }
    }
    __builtin_amdgcn_s_setprio(0);

    cur ^= 1;
  }

  // ---- epilogue: write unnormalized partial O (bf16) + partial l ----
  u16* po = po0 + (size_t)sp * ((size_t)B_ * N_ * 512);
  if (l16 == 0) {
    #pragma unroll
    for (int j = 0; j < 4; j++) {
      const int n = q0 + wave * 16 + lq * 4 + j;
      pl[((size_t)((sp * B_ + b) * H_) + h) * N_ + n] = lacc[j];
    }
  }
  #pragma unroll
  for (int di = 0; di < 4; di++)
    #pragma unroll
    for (int j = 0; j < 4; j++) {
      const int n = q0 + wave * 16 + lq * 4 + j;
      po[((size_t)(b * N_) + n) * 512 + h * D_ + di * 16 + l16] = f2bf(acc[di][j]);
    }
}

extern "C" void kernel_launch(void* const* d_in, const int* in_sizes, int n_in,
                              void* d_out, int out_size, void* d_ws, size_t ws_size,
                              hipStream_t stream) {
  const float* x     = (const float*)d_in[0];
  const float* gamma = (const float*)d_in[1];
  const float* beta  = (const float*)d_in[2];
  const float* w_qkv = (const float*)d_in[3];
  const float* w_out = (const float*)d_in[4];
  const float* b_out = (const float*)d_in[5];
  float* out = (float*)d_out;

  char* ws = (char*)d_ws;
  u16*    xT     = (u16*)(ws + 0);          // dead after gemm_qkv
  u16*    wq_bf  = (u16*)(ws + 9437184);
  u16*    po0    = (u16*)(ws + 11010048);
  u16*    po1    = (u16*)(ws + 20447232);
  u16*    vsec   = (u16*)(ws + 37748736);
  u16*    qT     = (u16*)(ws + 47185920);
  u16*    kT     = (u16*)(ws + 56623104);
  float*  pl     = (float*)(ws + 66060288);
  float2* part   = (float2*)(ws + 66650112);
  u16*    wo_bf  = (u16*)(ws + 66686976);
  float2* scsh   = (float2*)(ws + 67211264);

  prep_all<<<dim3(1408), dim3(256), 0, stream>>>(w_qkv, w_out, wq_bf, wo_bf, x, xT, part);
  make_scsh<<<dim3(B_), dim3(512), 0, stream>>>(part, gamma, beta, scsh);
  gemm_qkv<<<dim3(6, 18, B_), dim3(512), 0, stream>>>(wq_bf, xT, scsh, qT, kT, vsec);
  attn_kernel24<<<dim3(H_, N_ / 128, B_ * SPLIT), dim3(512), 0, stream>>>(qT, kT, vsec, po0, pl);
  gemm_out_fused<<<dim3(2, 18, B_), dim3(512), 0, stream>>>(wo_bf, po0, po1, pl, out, b_out);
}

// Round 26
// 116.484 us; speedup vs baseline: 1.1991x; 1.0134x over previous
//
#include <hip/hip_runtime.h>
#include <hip/hip_bf16.h>

// SelfAttention fused pipeline, bf16 MFMA path, K-split flash attention.
// x[4,512,48,48] -> GN(32) -> qkv 1x1 conv -> 8-head attn (N=2304,D=64) -> out proj.
// GN folded as per-channel affine into gemm_qkv's B staging (single x pass);
// final-norm (po0+po1)/l fused into the out-proj GEMM's B staging; l computed
// via ones-MFMA. Out-proj: 256x64 tile, grid 288 (2x parallelism vs 256x128).
//
// ws layout (67.23 MB < 68.16 MB proven safe):
//   xT    [4][2304][512] bf16 @ 0          (RAW x cast+transpose; dead after gemm_qkv)
//   wq_bf [1536][512] bf16    @ 9437184
//   po0   [4][2304][512] bf16 @ 11010048   (unnormalized partial O, split 0)
//   po1   [4][2304][512] bf16 @ 20447232   (split 1)
//   vsec  [4][512][2304] bf16 @ 37748736   (d-major, n-PERMUTED per 64-group)
//   qT    [4][8][2304][64] bf16 @ 47185920 (QSCALE folded at cast)
//   kT    [4][8][2304][64] bf16 @ 56623104
//   pl    [2][4][8][2304] f32  @ 66060288
//   part  [4][32][36] float2   @ 66650112  (GN partial sums per n-tile)
//   wo_bf [512][512] bf16      @ 66686976
//   scsh  [4][512] float2      @ 67211264  (GN affine: xn = x*sc + sh)

typedef unsigned short u16;
typedef unsigned int u32;
typedef __attribute__((ext_vector_type(8))) short bf16x8;
typedef __attribute__((ext_vector_type(4))) float f32x4;
typedef __attribute__((ext_vector_type(8))) unsigned short us8;
typedef __attribute__((ext_vector_type(4))) unsigned short us4;

#define B_ 4
#define C_ 512
#define N_ 2304
#define H_ 8
#define D_ 64
#define G_ 32
#define SPLIT 2
#define NT (N_ / 64 / SPLIT)   // 18 k-tiles per split block

// log2(e)/8: folded into W_q at cast so QK^T lands in exp2 domain.
#define QSCALE 0.1803368801111204f
// No max subtraction: exp2-domain scores |s| <~ 12, exp2(s) <= ~4096 fits f32/bf16;
// softmax is shift-invariant.

__device__ __forceinline__ u16 f2bf(float f) {
  unsigned u = __float_as_uint(f);
  u += 0x7FFFu + ((u >> 16) & 1u);   // RNE
  return (u16)(u >> 16);
}
__device__ __forceinline__ float bf2f(u16 h) {
  return __uint_as_float(((unsigned)h) << 16);
}
__device__ __forceinline__ u32 pack2bf(float lo, float hi) {
  __hip_bfloat162 t = __float22bfloat162_rn(float2{lo, hi});
  u32 r;
  __builtin_memcpy(&r, &t, 4);
  return r;
}

// async global->LDS, 16B per lane. LDS dest = wave-uniform base + lane*16.
__device__ __forceinline__ void gload16(const void* g, void* l) {
  __builtin_amdgcn_global_load_lds(
      reinterpret_cast<const __attribute__((address_space(1))) unsigned int*>(
          reinterpret_cast<unsigned long long>(g)),
      reinterpret_cast<__attribute__((address_space(3))) unsigned int*>(
          static_cast<unsigned int>(reinterpret_cast<unsigned long long>(l))),
      16, 0, 0);
}

// ---------------- prep: weight cast (blocks 0-255) + x cast/transpose + GN partials ----------------
__global__ __launch_bounds__(256) void prep_all(
    const float* __restrict__ wq, const float* __restrict__ wo,
    u16* __restrict__ wq_bf, u16* __restrict__ wo_bf,
    const float* __restrict__ x, u16* __restrict__ xT, float2* __restrict__ part) {
  if (blockIdx.x < 256) {
    const int n1 = 1536 * 512 / 4, n2 = 512 * 512 / 4;
    const int nq = 512 * 512 / 4;   // q section in float4 units
    for (int i = blockIdx.x * 256 + threadIdx.x; i < n1 + n2; i += 256 * 256) {
      const float4 v = (i < n1) ? ((const float4*)wq)[i] : ((const float4*)wo)[i - n1];
      const float sc = (i < nq) ? QSCALE : 1.0f;
      us4 o; o[0] = f2bf(v.x * sc); o[1] = f2bf(v.y * sc); o[2] = f2bf(v.z * sc); o[3] = f2bf(v.w * sc);
      if (i < n1) ((us4*)wq_bf)[i] = o; else ((us4*)wo_bf)[i - n1] = o;
    }
    return;
  }
  __shared__ u16 T[64][72];
  const int bid = blockIdx.x - 256;            // 0..1151
  const int b = bid / 288, rem = bid % 288;
  const int c0 = (rem & 7) * 64, ni = rem >> 3;   // ni = n-tile 0..35
  const int n0 = ni * 64;
  const int tid = threadIdx.x;
  const int r = tid >> 2, ch = (tid & 3) * 16;
  const float* src = x + (size_t)(b * C_ + c0 + r) * N_ + n0 + ch;
  float s = 0.f, s2 = 0.f;
  #pragma unroll
  for (int j = 0; j < 16; j += 4) {
    const float4 v = *(const float4*)(src + j);
    s  += v.x + v.y + v.z + v.w;
    s2 += v.x * v.x + v.y * v.y + v.z * v.z + v.w * v.w;
    us4 o; o[0] = f2bf(v.x); o[1] = f2bf(v.y); o[2] = f2bf(v.z); o[3] = f2bf(v.w);
    *(us4*)&T[r][ch + j] = o;
  }
  // wave w = c-rows 16w..16w+15 = one group quarter; reduce across 64 lanes
  #pragma unroll
  for (int off = 32; off; off >>= 1) { s += __shfl_xor(s, off); s2 += __shfl_xor(s2, off); }
  if ((tid & 63) == 0) {
    const int g = (c0 >> 4) + (tid >> 6);
    part[((size_t)(b * G_) + g) * 36 + ni] = make_float2(s, s2);
  }
  __syncthreads();
  us8 o1, o2;
  #pragma unroll
  for (int j = 0; j < 8; j++) { o1[j] = T[ch + j][r]; o2[j] = T[ch + 8 + j][r]; }
  u16* dst = xT + (size_t)(b * N_ + n0 + r) * C_ + c0 + ch;
  *(us8*)dst = o1;
  *(us8*)(dst + 8) = o2;
}

// ---------------- finalize GN stats -> scsh[b][c] = (sc, sh) ----------------
__global__ __launch_bounds__(512) void make_scsh(
    const float2* __restrict__ part, const float* __restrict__ gamma,
    const float* __restrict__ beta, float2* __restrict__ scsh) {
  const int b = blockIdx.x, c = threadIdx.x;
  const float2* pp = part + (size_t)(b * G_ + (c >> 4)) * 36;
  float S = 0.f, S2 = 0.f;
  #pragma unroll 4
  for (int i = 0; i < 36; i++) { S += pp[i].x; S2 += pp[i].y; }
  const float inv = 1.f / (16.f * N_);
  const float mean = S * inv;
  const float rstd = rsqrtf(S2 * inv - mean * mean + 1e-5f);
  const float sc = rstd * gamma[c];
  scsh[b * C_ + c] = make_float2(sc, beta[c] - mean * sc);
}

// ---------------- QKV GEMM: 256x128 tile, BK=64, GN affine fused in B staging ----------------
__global__ __launch_bounds__(512) void gemm_qkv(
    const u16* __restrict__ A, const u16* __restrict__ xT,
    const float2* __restrict__ scsh,
    u16* __restrict__ qT, u16* __restrict__ kT, u16* __restrict__ vout) {
  __shared__ u16 As[256][64];
  __shared__ u16 Bs[128][64];
  const int tid = threadIdx.x;
  const int wave = tid >> 6, lane = tid & 63;
  const int l16 = lane & 15, lq = lane >> 4;

  // XCD-chunked bijective block swizzle over grid (6,18,4) = 432 (432%8==0).
  const int lin = blockIdx.x + 6 * (blockIdx.y + 18 * blockIdx.z);
  const int per = 432 >> 3;
  const int eff = (lin & 7) * per + (lin >> 3);
  const int m0 = (eff % 6) * 256;
  const int n0 = ((eff / 6) % 18) * 128;
  const int bz = eff / 108;

  const int wm = (wave >> 1) * 64, wn = (wave & 1) * 64;
  const u16* Bb = xT + (size_t)bz * N_ * C_;
  const float2* sb = scsh + bz * C_;

  f32x4 acc[4][4];
  #pragma unroll
  for (int mi = 0; mi < 4; mi++)
    #pragma unroll
    for (int ni = 0; ni < 4; ni++) {
      acc[mi][ni][0] = 0.f; acc[mi][ni][1] = 0.f; acc[mi][ni][2] = 0.f; acc[mi][ni][3] = 0.f;
    }

  const int h3r = lane >> 3;                 // row-within-8 this lane covers
  const int scg = ((lane & 7) ^ h3r) * 8;    // pre-swizzled global chunk (A)
  const int rdx = l16 & 7;                   // read-side XOR key
  for (int kt = 0; kt < C_; kt += 64) {
    __syncthreads();
    #pragma unroll
    for (int j = 0; j < 4; j++) {
      const int row = wave * 8 + j * 64 + h3r;   // (row & 7) == h3r
      gload16(&A[(size_t)(m0 + row) * C_ + kt + scg], &As[wave * 8 + j * 64][0]);
    }
    // B staging: raw xT us8 (linear chunk) -> GN affine -> swizzled ds_write
    {
      const int cbase = kt + (lane & 7) * 8;
      float2 sv[8];
      #pragma unroll
      for (int e = 0; e < 8; e++) sv[e] = sb[cbase + e];
      #pragma unroll
      for (int j = 0; j < 2; j++) {
        const int row = wave * 8 + j * 64 + h3r;
        const us8 xr = *(const us8*)&Bb[(size_t)(n0 + row) * C_ + cbase];
        us8 o;
        #pragma unroll
        for (int e = 0; e < 8; e++) o[e] = f2bf(bf2f(xr[e]) * sv[e].x + sv[e].y);
        *(us8*)&Bs[row][((lane & 7) ^ h3r) * 8] = o;
      }
    }
    __syncthreads();
    #pragma unroll
    for (int kk = 0; kk < 2; kk++) {
      bf16x8 af[4], bfr[4];
      #pragma unroll
      for (int mi = 0; mi < 4; mi++)
        af[mi] = *(const bf16x8*)&As[wm + mi * 16 + l16][(((kk << 2) | lq) ^ rdx) * 8];
      #pragma unroll
      for (int ni = 0; ni < 4; ni++)
        bfr[ni] = *(const bf16x8*)&Bs[wn + ni * 16 + l16][(((kk << 2) | lq) ^ rdx) * 8];
      #pragma unroll
      for (int mi = 0; mi < 4; mi++)
        #pragma unroll
        for (int ni = 0; ni < 4; ni++)
          acc[mi][ni] = __builtin_amdgcn_mfma_f32_16x16x32_bf16(af[mi], bfr[ni], acc[mi][ni], 0, 0, 0);
    }
  }
  #pragma unroll
  for (int mi = 0; mi < 4; mi++) {
    const int row0 = m0 + wm + mi * 16 + lq * 4;
    #pragma unroll
    for (int ni = 0; ni < 4; ni++) {
      const int col = n0 + wn + ni * 16 + l16;
      const int which = row0 >> 9;           // 0=q, 1=k, 2=v
      if (which < 2) {
        const int h = (row0 >> 6) & 7, d0 = row0 & 63;
        u16* dst = which ? kT : qT;
        us4 o;
        #pragma unroll
        for (int j = 0; j < 4; j++) o[j] = f2bf(acc[mi][ni][j]);
        *(us4*)&dst[((size_t)((bz * H_ + h) * N_) + col) * D_ + d0] = o;
      } else {
        // n-permute within 64-group: n = g32 + hi*16 + lq2*4 + j -> g32 + lq2*8 + hi*4 + j
        const int cp = (col & ~63) | (col & 32) | (((col >> 2) & 3) << 3) |
                       (((col >> 4) & 1) << 2) | (col & 3);
        #pragma unroll
        for (int j = 0; j < 4; j++)
          vout[((size_t)(bz * 512) + (row0 & 511) + j) * N_ + cp] = f2bf(acc[mi][ni][j]);
      }
    }
  }
}

// ---------------- out-proj GEMM, 256x64 tile, 512 threads, fused combine ----------------
// out[bz][m][n] = wo_bf[m][k] * ((po0+po1)[bz][n][k] / l[bz][n]) + bias; f32 out.
// 8 waves split 4m x 2n (wave sub-tile 64x32); grid (2,36,4)=288 -> 1.125 blocks/CU.
__global__ __launch_bounds__(512) void gemm_out_fused(
    const u16* __restrict__ A, const u16* __restrict__ po0, const u16* __restrict__ po1,
    const float* __restrict__ pl, float* __restrict__ C, const float* __restrict__ bias) {
  __shared__ u16 As[256][64];
  __shared__ u16 Bs[64][64];
  const int tid = threadIdx.x;
  const int wave = tid >> 6, lane = tid & 63;
  const int l16 = lane & 15, lq = lane >> 4;

  // XCD-chunked bijective swizzle over grid (2,36,4) = 288 (288%8==0).
  const int lin = blockIdx.x + 2 * (blockIdx.y + 36 * blockIdx.z);
  const int per = 288 >> 3;
  const int eff = (lin & 7) * per + (lin >> 3);
  const int m0 = (eff % 2) * 256;
  const int n0 = ((eff / 2) % 36) * 64;
  const int bz = eff / 72;

  const int wm = (wave >> 1) * 64, wn = (wave & 1) * 32;

  f32x4 acc[4][2];
  #pragma unroll
  for (int mi = 0; mi < 4; mi++)
    #pragma unroll
    for (int ni = 0; ni < 2; ni++) {
      acc[mi][ni][0] = 0.f; acc[mi][ni][1] = 0.f; acc[mi][ni][2] = 0.f; acc[mi][ni][3] = 0.f;
    }

  const int h3r = lane >> 3;                 // row-within-8 this lane covers
  const int scg = ((lane & 7) ^ h3r) * 8;    // pre-swizzled global chunk (A)
  const int rdx = l16 & 7;                   // read-side XOR key
  const size_t lstr = (size_t)B_ * H_ * N_;
  for (int kt = 0; kt < C_; kt += 64) {
    __syncthreads();
    // A staging: global_load_lds, pre-swizzled source (256 rows, 4 issues/wave)
    #pragma unroll
    for (int j = 0; j < 4; j++) {
      const int row = wave * 8 + j * 64 + h3r;
      gload16(&A[(size_t)(m0 + row) * C_ + kt + scg], &As[wave * 8 + j * 64][0]);
    }
    // B staging: reg-staged combine+norm (64 rows, 1 pass/wave)
    {
      const int row = wave * 8 + h3r;
      const size_t pbase = ((size_t)(bz * N_) + n0 + row) * 512 + kt + (lane & 7) * 8;
      const us8 a = *(const us8*)&po0[pbase];
      const us8 c2 = *(const us8*)&po1[pbase];
      const size_t lidx = ((size_t)(bz * H_) + (kt >> 6)) * N_ + n0 + row;
      const float rl = 1.0f / (pl[lidx] + pl[lidx + lstr]);
      us8 o;
      #pragma unroll
      for (int e = 0; e < 8; e++) o[e] = f2bf((bf2f(a[e]) + bf2f(c2[e])) * rl);
      *(us8*)&Bs[row][((lane & 7) ^ h3r) * 8] = o;
    }
    __syncthreads();
    #pragma unroll
    for (int kk = 0; kk < 2; kk++) {
      bf16x8 af[4], bfr[2];
      #pragma unroll
      for (int mi = 0; mi < 4; mi++)
        af[mi] = *(const bf16x8*)&As[wm + mi * 16 + l16][(((kk << 2) | lq) ^ rdx) * 8];
      #pragma unroll
      for (int ni = 0; ni < 2; ni++)
        bfr[ni] = *(const bf16x8*)&Bs[wn + ni * 16 + l16][(((kk << 2) | lq) ^ rdx) * 8];
      #pragma unroll
      for (int mi = 0; mi < 4; mi++)
        #pragma unroll
        for (int ni = 0; ni < 2; ni++)
          acc[mi][ni] = __builtin_amdgcn_mfma_f32_16x16x32_bf16(af[mi], bfr[ni], acc[mi][ni], 0, 0, 0);
    }
  }
  #pragma unroll
  for (int mi = 0; mi < 4; mi++) {
    const int row0 = m0 + wm + mi * 16 + lq * 4;
    #pragma unroll
    for (int ni = 0; ni < 2; ni++) {
      const int col = n0 + wn + ni * 16 + l16;
      #pragma unroll
      for (int j = 0; j < 4; j++) {
        const size_t idx = ((size_t)bz * C_ + row0 + j) * N_ + col;
        C[idx] = acc[mi][ni][j] + bias[row0 + j];
      }
    }
  }
}

// ---------------- flash attention v24: SPLIT=2 + l via ones-MFMA (unchanged) ----------------
__global__ __launch_bounds__(512) void attn_kernel24(
    const u16* __restrict__ qT, const u16* __restrict__ kT,
    const u16* __restrict__ vp, u16* __restrict__ po0,
    float* __restrict__ pl) {
  __shared__ u16 Ks[2][64][64];
  __shared__ u16 Vs[2][64][64];

  const int h = blockIdx.x;
  const int b = blockIdx.z >> 1, sp = blockIdx.z & 1;
  const int q0 = blockIdx.y * 128;
  const int tid = threadIdx.x;
  const int wave = tid >> 6, lane = tid & 63;
  const int l16 = lane & 15, lq = lane >> 4;
  const int h3 = l16 & 7;                  // read-side XOR key
  const int kt0 = sp * NT;

  bf16x8 qf[2];
  {
    const u16* qb = qT + ((size_t)((b * H_ + h) * N_ + q0 + wave * 16 + l16)) * D_;
    qf[0] = *(const bf16x8*)(qb + lq * 8);
    qf[1] = *(const bf16x8*)(qb + 32 + lq * 8);
  }

  f32x4 acc[4], lacc;
  #pragma unroll
  for (int di = 0; di < 4; di++) {
    acc[di][0] = 0.f; acc[di][1] = 0.f; acc[di][2] = 0.f; acc[di][3] = 0.f;
  }
  lacc[0] = 0.f; lacc[1] = 0.f; lacc[2] = 0.f; lacc[3] = 0.f;
  const f32x4 z4 = {0.f, 0.f, 0.f, 0.f};
  union { u32 w[4]; bf16x8 v; } ones;
  ones.w[0] = 0x3F803F80u; ones.w[1] = 0x3F803F80u;
  ones.w[2] = 0x3F803F80u; ones.w[3] = 0x3F803F80u;

  const u16* kbase = kT + (size_t)(b * H_ + h) * N_ * D_;
  const u16* vbase = vp + ((size_t)(b * 512) + h * D_) * N_;
  const int srow = wave * 8 + (lane >> 3);
  const int scg  = (((lane & 7) ^ (srow & 7))) * 8;

  gload16(&kbase[(size_t)(kt0 * 64 + srow) * D_ + scg], &Ks[0][wave * 8][0]);
  gload16(&vbase[(size_t)srow * N_ + kt0 * 64 + scg],   &Vs[0][wave * 8][0]);

  int cur = 0;
  for (int t = 0; t < NT; t++) {
    const int kt = kt0 + t;
    __syncthreads();

    if (t + 1 < NT) {
      gload16(&kbase[(size_t)((kt + 1) * 64 + srow) * D_ + scg], &Ks[cur ^ 1][wave * 8][0]);
      gload16(&vbase[(size_t)srow * N_ + (kt + 1) * 64 + scg],   &Vs[cur ^ 1][wave * 8][0]);
    }

    // ---- S^T = K Q^T ----
    f32x4 s[4];
    __builtin_amdgcn_s_setprio(1);
    #pragma unroll
    for (int ni = 0; ni < 4; ni++) {
      const bf16x8 k0 = *(const bf16x8*)&Ks[cur][ni * 16 + l16][(lq ^ h3) * 8];
      const bf16x8 k1 = *(const bf16x8*)&Ks[cur][ni * 16 + l16][((4 | lq) ^ h3) * 8];
      s[ni] = __builtin_amdgcn_mfma_f32_16x16x32_bf16(k0, qf[0], z4, 0, 0, 0);
      s[ni] = __builtin_amdgcn_mfma_f32_16x16x32_bf16(k1, qf[1], s[ni], 0, 0, 0);
    }
    __builtin_amdgcn_s_setprio(0);

    // ---- p = exp2(s); pack directly into PV a-frag words (no VALU l-sum) ----
    union { u32 w[4]; bf16x8 v; } af[2];
    #pragma unroll
    for (int ni = 0; ni < 4; ni++) {
      const float p0 = __builtin_amdgcn_exp2f(s[ni][0]);
      const float p1 = __builtin_amdgcn_exp2f(s[ni][1]);
      const float p2 = __builtin_amdgcn_exp2f(s[ni][2]);
      const float p3 = __builtin_amdgcn_exp2f(s[ni][3]);
      af[ni >> 1].w[(ni & 1) * 2]     = pack2bf(p0, p1);
      af[ni >> 1].w[(ni & 1) * 2 + 1] = pack2bf(p2, p3);
    }

    // ---- PV + l (ones-MFMA sums p over all k-slots incl. cross-lane) ----
    __builtin_amdgcn_s_setprio(1);
    #pragma unroll
    for (int kh = 0; kh < 2; kh++) {
      lacc = __builtin_amdgcn_mfma_f32_16x16x32_bf16(af[kh].v, ones.v, lacc, 0, 0, 0);
      #pragma unroll
      for (int di = 0; di < 4; di++) {
        const bf16x8 vf = *(const bf16x8*)&Vs[cur][di * 16 + l16][(((kh << 2) | lq) ^ h3) * 8];
        acc[di] = __builtin_amdgcn_mfma_f32_16x16x32_bf16(af[kh].v, vf, acc[di], 0, 0, 0);
      }
    }
    __builtin_amdgcn_s_setprio(0);

    cur ^= 1;
  }

  // ---- epilogue: write unnormalized partial O (bf16) + partial l ----
  u16* po = po0 + (size_t)sp * ((size_t)B_ * N_ * 512);
  if (l16 == 0) {
    #pragma unroll
    for (int j = 0; j < 4; j++) {
      const int n = q0 + wave * 16 + lq * 4 + j;
      pl[((size_t)((sp * B_ + b) * H_) + h) * N_ + n] = lacc[j];
    }
  }
  #pragma unroll
  for (int di = 0; di < 4; di++)
    #pragma unroll
    for (int j = 0; j < 4; j++) {
      const int n = q0 + wave * 16 + lq * 4 + j;
      po[((size_t)(b * N_) + n) * 512 + h * D_ + di * 16 + l16] = f2bf(acc[di][j]);
    }
}

extern "C" void kernel_launch(void* const* d_in, const int* in_sizes, int n_in,
                              void* d_out, int out_size, void* d_ws, size_t ws_size,
                              hipStream_t stream) {
  const float* x     = (const float*)d_in[0];
  const float* gamma = (const float*)d_in[1];
  const float* beta  = (const float*)d_in[2];
  const float* w_qkv = (const float*)d_in[3];
  const float* w_out = (const float*)d_in[4];
  const float* b_out = (const float*)d_in[5];
  float* out = (float*)d_out;

  char* ws = (char*)d_ws;
  u16*    xT     = (u16*)(ws + 0);          // dead after gemm_qkv
  u16*    wq_bf  = (u16*)(ws + 9437184);
  u16*    po0    = (u16*)(ws + 11010048);
  u16*    po1    = (u16*)(ws + 20447232);
  u16*    vsec   = (u16*)(ws + 37748736);
  u16*    qT     = (u16*)(ws + 47185920);
  u16*    kT     = (u16*)(ws + 56623104);
  float*  pl     = (float*)(ws + 66060288);
  float2* part   = (float2*)(ws + 66650112);
  u16*    wo_bf  = (u16*)(ws + 66686976);
  float2* scsh   = (float2*)(ws + 67211264);

  prep_all<<<dim3(1408), dim3(256), 0, stream>>>(w_qkv, w_out, wq_bf, wo_bf, x, xT, part);
  make_scsh<<<dim3(B_), dim3(512), 0, stream>>>(part, gamma, beta, scsh);
  gemm_qkv<<<dim3(6, 18, B_), dim3(512), 0, stream>>>(wq_bf, xT, scsh, qT, kT, vsec);
  attn_kernel24<<<dim3(H_, N_ / 128, B_ * SPLIT), dim3(512), 0, stream>>>(qT, kT, vsec, po0, pl);
  gemm_out_fused<<<dim3(2, 36, B_), dim3(512), 0, stream>>>(wo_bf, po0, po1, pl, out, b_out);
}

// Round 27
// 114.341 us; speedup vs baseline: 1.2216x; 1.0187x over previous
//
#include <hip/hip_runtime.h>
#include <hip/hip_bf16.h>

// SelfAttention fused pipeline, bf16 MFMA path, K-split flash attention.
// x[4,512,48,48] -> GN(32) -> qkv 1x1 conv -> 8-head attn (N=2304,D=64) -> out proj.
// GN folded as per-channel affine into gemm_qkv's B staging (single x pass;
// stats finalized in gemm_qkv's prologue); final-norm (po0+po1)/l fused into
// the out-proj GEMM's B staging; l computed via ones-MFMA.
//
// ws layout (67.22 MB < 68.16 MB proven safe):
//   xT    [4][2304][512] bf16 @ 0          (RAW x cast+transpose; dead after gemm_qkv)
//   wq_bf [1536][512] bf16    @ 9437184
//   po0   [4][2304][512] bf16 @ 11010048   (unnormalized partial O, split 0)
//   po1   [4][2304][512] bf16 @ 20447232   (split 1)
//   vsec  [4][512][2304] bf16 @ 37748736   (d-major, n-PERMUTED per 64-group)
//   qT    [4][8][2304][64] bf16 @ 47185920 (QSCALE folded at cast)
//   kT    [4][8][2304][64] bf16 @ 56623104
//   pl    [2][4][8][2304] f32  @ 66060288
//   part  [4][32][36] float2   @ 66650112  (GN partial sums per n-tile)
//   wo_bf [512][512] bf16      @ 66686976

typedef unsigned short u16;
typedef unsigned int u32;
typedef __attribute__((ext_vector_type(8))) short bf16x8;
typedef __attribute__((ext_vector_type(4))) float f32x4;
typedef __attribute__((ext_vector_type(8))) unsigned short us8;
typedef __attribute__((ext_vector_type(4))) unsigned short us4;

#define B_ 4
#define C_ 512
#define N_ 2304
#define H_ 8
#define D_ 64
#define G_ 32
#define SPLIT 2
#define NT (N_ / 64 / SPLIT)   // 18 k-tiles per split block

// log2(e)/8: folded into W_q at cast so QK^T lands in exp2 domain.
#define QSCALE 0.1803368801111204f
// No max subtraction: exp2-domain scores |s| <~ 12, exp2(s) <= ~4096 fits f32/bf16;
// softmax is shift-invariant.

__device__ __forceinline__ u16 f2bf(float f) {
  unsigned u = __float_as_uint(f);
  u += 0x7FFFu + ((u >> 16) & 1u);   // RNE
  return (u16)(u >> 16);
}
__device__ __forceinline__ float bf2f(u16 h) {
  return __uint_as_float(((unsigned)h) << 16);
}
__device__ __forceinline__ u32 pack2bf(float lo, float hi) {
  __hip_bfloat162 t = __float22bfloat162_rn(float2{lo, hi});
  u32 r;
  __builtin_memcpy(&r, &t, 4);
  return r;
}

// async global->LDS, 16B per lane. LDS dest = wave-uniform base + lane*16.
__device__ __forceinline__ void gload16(const void* g, void* l) {
  __builtin_amdgcn_global_load_lds(
      reinterpret_cast<const __attribute__((address_space(1))) unsigned int*>(
          reinterpret_cast<unsigned long long>(g)),
      reinterpret_cast<__attribute__((address_space(3))) unsigned int*>(
          static_cast<unsigned int>(reinterpret_cast<unsigned long long>(l))),
      16, 0, 0);
}

// ---------------- prep: weight cast (blocks 0-255) + x cast/transpose + GN partials ----------------
__global__ __launch_bounds__(256) void prep_all(
    const float* __restrict__ wq, const float* __restrict__ wo,
    u16* __restrict__ wq_bf, u16* __restrict__ wo_bf,
    const float* __restrict__ x, u16* __restrict__ xT, float2* __restrict__ part) {
  if (blockIdx.x < 256) {
    const int n1 = 1536 * 512 / 4, n2 = 512 * 512 / 4;
    const int nq = 512 * 512 / 4;   // q section in float4 units
    for (int i = blockIdx.x * 256 + threadIdx.x; i < n1 + n2; i += 256 * 256) {
      const float4 v = (i < n1) ? ((const float4*)wq)[i] : ((const float4*)wo)[i - n1];
      const float sc = (i < nq) ? QSCALE : 1.0f;
      us4 o; o[0] = f2bf(v.x * sc); o[1] = f2bf(v.y * sc); o[2] = f2bf(v.z * sc); o[3] = f2bf(v.w * sc);
      if (i < n1) ((us4*)wq_bf)[i] = o; else ((us4*)wo_bf)[i - n1] = o;
    }
    return;
  }
  __shared__ u16 T[64][72];
  const int bid = blockIdx.x - 256;            // 0..1151
  const int b = bid / 288, rem = bid % 288;
  const int c0 = (rem & 7) * 64, ni = rem >> 3;   // ni = n-tile 0..35
  const int n0 = ni * 64;
  const int tid = threadIdx.x;
  const int r = tid >> 2, ch = (tid & 3) * 16;
  const float* src = x + (size_t)(b * C_ + c0 + r) * N_ + n0 + ch;
  float s = 0.f, s2 = 0.f;
  #pragma unroll
  for (int j = 0; j < 16; j += 4) {
    const float4 v = *(const float4*)(src + j);
    s  += v.x + v.y + v.z + v.w;
    s2 += v.x * v.x + v.y * v.y + v.z * v.z + v.w * v.w;
    us4 o; o[0] = f2bf(v.x); o[1] = f2bf(v.y); o[2] = f2bf(v.z); o[3] = f2bf(v.w);
    *(us4*)&T[r][ch + j] = o;
  }
  // wave w = c-rows 16w..16w+15 = one group quarter; reduce across 64 lanes
  #pragma unroll
  for (int off = 32; off; off >>= 1) { s += __shfl_xor(s, off); s2 += __shfl_xor(s2, off); }
  if ((tid & 63) == 0) {
    const int g = (c0 >> 4) + (tid >> 6);
    part[((size_t)(b * G_) + g) * 36 + ni] = make_float2(s, s2);
  }
  __syncthreads();
  us8 o1, o2;
  #pragma unroll
  for (int j = 0; j < 8; j++) { o1[j] = T[ch + j][r]; o2[j] = T[ch + 8 + j][r]; }
  u16* dst = xT + (size_t)(b * N_ + n0 + r) * C_ + c0 + ch;
  *(us8*)dst = o1;
  *(us8*)(dst + 8) = o2;
}

// ---------------- QKV GEMM: 256x128 tile, BK=64, GN affine fused in B staging ----------------
// Prologue: each of the 512 threads reduces its channel's 36 GN partials and
// writes scshs[c] = (sc, sh) into LDS (first k-loop barrier orders it).
__global__ __launch_bounds__(512) void gemm_qkv(
    const u16* __restrict__ A, const u16* __restrict__ xT,
    const float2* __restrict__ part, const float* __restrict__ gamma,
    const float* __restrict__ beta,
    u16* __restrict__ qT, u16* __restrict__ kT, u16* __restrict__ vout) {
  __shared__ u16 As[256][64];
  __shared__ u16 Bs[128][64];
  __shared__ float2 scshs[512];
  const int tid = threadIdx.x;
  const int wave = tid >> 6, lane = tid & 63;
  const int l16 = lane & 15, lq = lane >> 4;

  // XCD-chunked bijective block swizzle over grid (6,18,4) = 432 (432%8==0).
  const int lin = blockIdx.x + 6 * (blockIdx.y + 18 * blockIdx.z);
  const int per = 432 >> 3;
  const int eff = (lin & 7) * per + (lin >> 3);
  const int m0 = (eff % 6) * 256;
  const int n0 = ((eff / 6) % 18) * 128;
  const int bz = eff / 108;

  // finalize GN stats for this batch into LDS (one channel per thread)
  {
    const int c = tid;
    const float2* pp = part + (size_t)(bz * G_ + (c >> 4)) * 36;
    float S = 0.f, S2 = 0.f;
    #pragma unroll 4
    for (int i = 0; i < 36; i++) { S += pp[i].x; S2 += pp[i].y; }
    const float inv = 1.f / (16.f * N_);
    const float mean = S * inv;
    const float rstd = rsqrtf(S2 * inv - mean * mean + 1e-5f);
    const float sc = rstd * gamma[c];
    scshs[c] = make_float2(sc, beta[c] - mean * sc);
  }

  const int wm = (wave >> 1) * 64, wn = (wave & 1) * 64;
  const u16* Bb = xT + (size_t)bz * N_ * C_;

  f32x4 acc[4][4];
  #pragma unroll
  for (int mi = 0; mi < 4; mi++)
    #pragma unroll
    for (int ni = 0; ni < 4; ni++) {
      acc[mi][ni][0] = 0.f; acc[mi][ni][1] = 0.f; acc[mi][ni][2] = 0.f; acc[mi][ni][3] = 0.f;
    }

  const int h3r = lane >> 3;                 // row-within-8 this lane covers
  const int scg = ((lane & 7) ^ h3r) * 8;    // pre-swizzled global chunk (A)
  const int rdx = l16 & 7;                   // read-side XOR key
  for (int kt = 0; kt < C_; kt += 64) {
    __syncthreads();                         // also orders scshs writes (first iter)
    #pragma unroll
    for (int j = 0; j < 4; j++) {
      const int row = wave * 8 + j * 64 + h3r;   // (row & 7) == h3r
      gload16(&A[(size_t)(m0 + row) * C_ + kt + scg], &As[wave * 8 + j * 64][0]);
    }
    // B staging: raw xT us8 (linear chunk) -> GN affine -> swizzled ds_write
    {
      const int cbase = kt + (lane & 7) * 8;
      float2 sv[8];
      #pragma unroll
      for (int e = 0; e < 8; e++) sv[e] = scshs[cbase + e];
      #pragma unroll
      for (int j = 0; j < 2; j++) {
        const int row = wave * 8 + j * 64 + h3r;
        const us8 xr = *(const us8*)&Bb[(size_t)(n0 + row) * C_ + cbase];
        us8 o;
        #pragma unroll
        for (int e = 0; e < 8; e++) o[e] = f2bf(bf2f(xr[e]) * sv[e].x + sv[e].y);
        *(us8*)&Bs[row][((lane & 7) ^ h3r) * 8] = o;
      }
    }
    __syncthreads();
    #pragma unroll
    for (int kk = 0; kk < 2; kk++) {
      bf16x8 af[4], bfr[4];
      #pragma unroll
      for (int mi = 0; mi < 4; mi++)
        af[mi] = *(const bf16x8*)&As[wm + mi * 16 + l16][(((kk << 2) | lq) ^ rdx) * 8];
      #pragma unroll
      for (int ni = 0; ni < 4; ni++)
        bfr[ni] = *(const bf16x8*)&Bs[wn + ni * 16 + l16][(((kk << 2) | lq) ^ rdx) * 8];
      #pragma unroll
      for (int mi = 0; mi < 4; mi++)
        #pragma unroll
        for (int ni = 0; ni < 4; ni++)
          acc[mi][ni] = __builtin_amdgcn_mfma_f32_16x16x32_bf16(af[mi], bfr[ni], acc[mi][ni], 0, 0, 0);
    }
  }
  #pragma unroll
  for (int mi = 0; mi < 4; mi++) {
    const int row0 = m0 + wm + mi * 16 + lq * 4;
    #pragma unroll
    for (int ni = 0; ni < 4; ni++) {
      const int col = n0 + wn + ni * 16 + l16;
      const int which = row0 >> 9;           // 0=q, 1=k, 2=v
      if (which < 2) {
        const int h = (row0 >> 6) & 7, d0 = row0 & 63;
        u16* dst = which ? kT : qT;
        us4 o;
        #pragma unroll
        for (int j = 0; j < 4; j++) o[j] = f2bf(acc[mi][ni][j]);
        *(us4*)&dst[((size_t)((bz * H_ + h) * N_) + col) * D_ + d0] = o;
      } else {
        // n-permute within 64-group: n = g32 + hi*16 + lq2*4 + j -> g32 + lq2*8 + hi*4 + j
        const int cp = (col & ~63) | (col & 32) | (((col >> 2) & 3) << 3) |
                       (((col >> 4) & 1) << 2) | (col & 3);
        #pragma unroll
        for (int j = 0; j < 4; j++)
          vout[((size_t)(bz * 512) + (row0 & 511) + j) * N_ + cp] = f2bf(acc[mi][ni][j]);
      }
    }
  }
}

// ---------------- out-proj GEMM, 256x64 tile, 512 threads, fused combine ----------------
// out[bz][m][n] = wo_bf[m][k] * ((po0+po1)[bz][n][k] / l[bz][n]) + bias; f32 out.
// 8 waves split 4m x 2n (wave sub-tile 64x32); grid (2,36,4)=288.
__global__ __launch_bounds__(512) void gemm_out_fused(
    const u16* __restrict__ A, const u16* __restrict__ po0, const u16* __restrict__ po1,
    const float* __restrict__ pl, float* __restrict__ C, const float* __restrict__ bias) {
  __shared__ u16 As[256][64];
  __shared__ u16 Bs[64][64];
  const int tid = threadIdx.x;
  const int wave = tid >> 6, lane = tid & 63;
  const int l16 = lane & 15, lq = lane >> 4;

  // XCD-chunked bijective swizzle over grid (2,36,4) = 288 (288%8==0).
  const int lin = blockIdx.x + 2 * (blockIdx.y + 36 * blockIdx.z);
  const int per = 288 >> 3;
  const int eff = (lin & 7) * per + (lin >> 3);
  const int m0 = (eff % 2) * 256;
  const int n0 = ((eff / 2) % 36) * 64;
  const int bz = eff / 72;

  const int wm = (wave >> 1) * 64, wn = (wave & 1) * 32;

  f32x4 acc[4][2];
  #pragma unroll
  for (int mi = 0; mi < 4; mi++)
    #pragma unroll
    for (int ni = 0; ni < 2; ni++) {
      acc[mi][ni][0] = 0.f; acc[mi][ni][1] = 0.f; acc[mi][ni][2] = 0.f; acc[mi][ni][3] = 0.f;
    }

  const int h3r = lane >> 3;                 // row-within-8 this lane covers
  const int scg = ((lane & 7) ^ h3r) * 8;    // pre-swizzled global chunk (A)
  const int rdx = l16 & 7;                   // read-side XOR key
  const size_t lstr = (size_t)B_ * H_ * N_;
  for (int kt = 0; kt < C_; kt += 64) {
    __syncthreads();
    // A staging: global_load_lds, pre-swizzled source (256 rows, 4 issues/wave)
    #pragma unroll
    for (int j = 0; j < 4; j++) {
      const int row = wave * 8 + j * 64 + h3r;
      gload16(&A[(size_t)(m0 + row) * C_ + kt + scg], &As[wave * 8 + j * 64][0]);
    }
    // B staging: reg-staged combine+norm (64 rows, 1 pass/wave)
    {
      const int row = wave * 8 + h3r;
      const size_t pbase = ((size_t)(bz * N_) + n0 + row) * 512 + kt + (lane & 7) * 8;
      const us8 a = *(const us8*)&po0[pbase];
      const us8 c2 = *(const us8*)&po1[pbase];
      const size_t lidx = ((size_t)(bz * H_) + (kt >> 6)) * N_ + n0 + row;
      const float rl = 1.0f / (pl[lidx] + pl[lidx + lstr]);
      us8 o;
      #pragma unroll
      for (int e = 0; e < 8; e++) o[e] = f2bf((bf2f(a[e]) + bf2f(c2[e])) * rl);
      *(us8*)&Bs[row][((lane & 7) ^ h3r) * 8] = o;
    }
    __syncthreads();
    #pragma unroll
    for (int kk = 0; kk < 2; kk++) {
      bf16x8 af[4], bfr[2];
      #pragma unroll
      for (int mi = 0; mi < 4; mi++)
        af[mi] = *(const bf16x8*)&As[wm + mi * 16 + l16][(((kk << 2) | lq) ^ rdx) * 8];
      #pragma unroll
      for (int ni = 0; ni < 2; ni++)
        bfr[ni] = *(const bf16x8*)&Bs[wn + ni * 16 + l16][(((kk << 2) | lq) ^ rdx) * 8];
      #pragma unroll
      for (int mi = 0; mi < 4; mi++)
        #pragma unroll
        for (int ni = 0; ni < 2; ni++)
          acc[mi][ni] = __builtin_amdgcn_mfma_f32_16x16x32_bf16(af[mi], bfr[ni], acc[mi][ni], 0, 0, 0);
    }
  }
  #pragma unroll
  for (int mi = 0; mi < 4; mi++) {
    const int row0 = m0 + wm + mi * 16 + lq * 4;
    #pragma unroll
    for (int ni = 0; ni < 2; ni++) {
      const int col = n0 + wn + ni * 16 + l16;
      #pragma unroll
      for (int j = 0; j < 4; j++) {
        const size_t idx = ((size_t)bz * C_ + row0 + j) * N_ + col;
        C[idx] = acc[mi][ni][j] + bias[row0 + j];
      }
    }
  }
}

// ---------------- flash attention v24: SPLIT=2 + l via ones-MFMA (unchanged) ----------------
__global__ __launch_bounds__(512) void attn_kernel24(
    const u16* __restrict__ qT, const u16* __restrict__ kT,
    const u16* __restrict__ vp, u16* __restrict__ po0,
    float* __restrict__ pl) {
  __shared__ u16 Ks[2][64][64];
  __shared__ u16 Vs[2][64][64];

  const int h = blockIdx.x;
  const int b = blockIdx.z >> 1, sp = blockIdx.z & 1;
  const int q0 = blockIdx.y * 128;
  const int tid = threadIdx.x;
  const int wave = tid >> 6, lane = tid & 63;
  const int l16 = lane & 15, lq = lane >> 4;
  const int h3 = l16 & 7;                  // read-side XOR key
  const int kt0 = sp * NT;

  bf16x8 qf[2];
  {
    const u16* qb = qT + ((size_t)((b * H_ + h) * N_ + q0 + wave * 16 + l16)) * D_;
    qf[0] = *(const bf16x8*)(qb + lq * 8);
    qf[1] = *(const bf16x8*)(qb + 32 + lq * 8);
  }

  f32x4 acc[4], lacc;
  #pragma unroll
  for (int di = 0; di < 4; di++) {
    acc[di][0] = 0.f; acc[di][1] = 0.f; acc[di][2] = 0.f; acc[di][3] = 0.f;
  }
  lacc[0] = 0.f; lacc[1] = 0.f; lacc[2] = 0.f; lacc[3] = 0.f;
  const f32x4 z4 = {0.f, 0.f, 0.f, 0.f};
  union { u32 w[4]; bf16x8 v; } ones;
  ones.w[0] = 0x3F803F80u; ones.w[1] = 0x3F803F80u;
  ones.w[2] = 0x3F803F80u; ones.w[3] = 0x3F803F80u;

  const u16* kbase = kT + (size_t)(b * H_ + h) * N_ * D_;
  const u16* vbase = vp + ((size_t)(b * 512) + h * D_) * N_;
  const int srow = wave * 8 + (lane >> 3);
  const int scg  = (((lane & 7) ^ (srow & 7))) * 8;

  gload16(&kbase[(size_t)(kt0 * 64 + srow) * D_ + scg], &Ks[0][wave * 8][0]);
  gload16(&vbase[(size_t)srow * N_ + kt0 * 64 + scg],   &Vs[0][wave * 8][0]);

  int cur = 0;
  for (int t = 0; t < NT; t++) {
    const int kt = kt0 + t;
    __syncthreads();

    if (t + 1 < NT) {
      gload16(&kbase[(size_t)((kt + 1) * 64 + srow) * D_ + scg], &Ks[cur ^ 1][wave * 8][0]);
      gload16(&vbase[(size_t)srow * N_ + (kt + 1) * 64 + scg],   &Vs[cur ^ 1][wave * 8][0]);
    }

    // ---- S^T = K Q^T ----
    f32x4 s[4];
    __builtin_amdgcn_s_setprio(1);
    #pragma unroll
    for (int ni = 0; ni < 4; ni++) {
      const bf16x8 k0 = *(const bf16x8*)&Ks[cur][ni * 16 + l16][(lq ^ h3) * 8];
      const bf16x8 k1 = *(const bf16x8*)&Ks[cur][ni * 16 + l16][((4 | lq) ^ h3) * 8];
      s[ni] = __builtin_amdgcn_mfma_f32_16x16x32_bf16(k0, qf[0], z4, 0, 0, 0);
      s[ni] = __builtin_amdgcn_mfma_f32_16x16x32_bf16(k1, qf[1], s[ni], 0, 0, 0);
    }
    __builtin_amdgcn_s_setprio(0);

    // ---- p = exp2(s); pack directly into PV a-frag words (no VALU l-sum) ----
    union { u32 w[4]; bf16x8 v; } af[2];
    #pragma unroll
    for (int ni = 0; ni < 4; ni++) {
      const float p0 = __builtin_amdgcn_exp2f(s[ni][0]);
      const float p1 = __builtin_amdgcn_exp2f(s[ni][1]);
      const float p2 = __builtin_amdgcn_exp2f(s[ni][2]);
      const float p3 = __builtin_amdgcn_exp2f(s[ni][3]);
      af[ni >> 1].w[(ni & 1) * 2]     = pack2bf(p0, p1);
      af[ni >> 1].w[(ni & 1) * 2 + 1] = pack2bf(p2, p3);
    }

    // ---- PV + l (ones-MFMA sums p over all k-slots incl. cross-lane) ----
    __builtin_amdgcn_s_setprio(1);
    #pragma unroll
    for (int kh = 0; kh < 2; kh++) {
      lacc = __builtin_amdgcn_mfma_f32_16x16x32_bf16(af[kh].v, ones.v, lacc, 0, 0, 0);
      #pragma unroll
      for (int di = 0; di < 4; di++) {
        const bf16x8 vf = *(const bf16x8*)&Vs[cur][di * 16 + l16][(((kh << 2) | lq) ^ h3) * 8];
        acc[di] = __builtin_amdgcn_mfma_f32_16x16x32_bf16(af[kh].v, vf, acc[di], 0, 0, 0);
      }
    }
    __builtin_amdgcn_s_setprio(0);

    cur ^= 1;
  }

  // ---- epilogue: write unnormalized partial O (bf16) + partial l ----
  u16* po = po0 + (size_t)sp * ((size_t)B_ * N_ * 512);
  if (l16 == 0) {
    #pragma unroll
    for (int j = 0; j < 4; j++) {
      const int n = q0 + wave * 16 + lq * 4 + j;
      pl[((size_t)((sp * B_ + b) * H_) + h) * N_ + n] = lacc[j];
    }
  }
  #pragma unroll
  for (int di = 0; di < 4; di++)
    #pragma unroll
    for (int j = 0; j < 4; j++) {
      const int n = q0 + wave * 16 + lq * 4 + j;
      po[((size_t)(b * N_) + n) * 512 + h * D_ + di * 16 + l16] = f2bf(acc[di][j]);
    }
}

extern "C" void kernel_launch(void* const* d_in, const int* in_sizes, int n_in,
                              void* d_out, int out_size, void* d_ws, size_t ws_size,
                              hipStream_t stream) {
  const float* x     = (const float*)d_in[0];
  const float* gamma = (const float*)d_in[1];
  const float* beta  = (const float*)d_in[2];
  const float* w_qkv = (const float*)d_in[3];
  const float* w_out = (const float*)d_in[4];
  const float* b_out = (const float*)d_in[5];
  float* out = (float*)d_out;

  char* ws = (char*)d_ws;
  u16*    xT     = (u16*)(ws + 0);          // dead after gemm_qkv
  u16*    wq_bf  = (u16*)(ws + 9437184);
  u16*    po0    = (u16*)(ws + 11010048);
  u16*    po1    = (u16*)(ws + 20447232);
  u16*    vsec   = (u16*)(ws + 37748736);
  u16*    qT     = (u16*)(ws + 47185920);
  u16*    kT     = (u16*)(ws + 56623104);
  float*  pl     = (float*)(ws + 66060288);
  float2* part   = (float2*)(ws + 66650112);
  u16*    wo_bf  = (u16*)(ws + 66686976);

  prep_all<<<dim3(1408), dim3(256), 0, stream>>>(w_qkv, w_out, wq_bf, wo_bf, x, xT, part);
  gemm_qkv<<<dim3(6, 18, B_), dim3(512), 0, stream>>>(wq_bf, xT, part, gamma, beta, qT, kT, vsec);
  attn_kernel24<<<dim3(H_, N_ / 128, B_ * SPLIT), dim3(512), 0, stream>>>(qT, kT, vsec, po0, pl);
  gemm_out_fused<<<dim3(2, 36, B_), dim3(512), 0, stream>>>(wo_bf, po0, po1, pl, out, b_out);
}